// Round 4
// baseline (250.346 us; speedup 1.0000x reference)
//
#include <hip/hip_runtime.h>
#include <math.h>

#define NB 8
#define CIN 256
#define SEQ 1024
#define NH 8
#define DH 64
#define HID 512
#define OQKV 1536

typedef __attribute__((ext_vector_type(8))) short short8;
typedef __attribute__((ext_vector_type(4))) short short4v;
typedef __attribute__((ext_vector_type(4))) float float4v;

static __device__ inline short f2bf(float x) {
    union { float f; unsigned u; } c; c.f = x;
    unsigned r = (c.u + 0x7FFFu + ((c.u >> 16) & 1u)) >> 16;
    return (short)r;
}
static __device__ inline float bf2f(short h) {
    union { unsigned u; float f; } c; c.u = ((unsigned)(unsigned short)h) << 16;
    return c.f;
}

// ============ MFMA GEMM: C[b,m,n] = sum_k A[m,k] * B[b,k,n] (+ bias[m]) =====
#define BN 128
#define BK 32
#define LP 36

template<int BM, int WAVES_M, int WM, int WN, bool BIAS>
__global__ __launch_bounds__(256) void gemm_mfma(const float* __restrict__ A,
                                                 const float* __restrict__ B,
                                                 const float* __restrict__ bias,
                                                 float* __restrict__ C,
                                                 int M, int K) {
    __shared__ __align__(16) short As[BM * LP];
    __shared__ __align__(16) short Bs[BN * LP];
    const int t = threadIdx.x;
    const int lane = t & 63, wv = t >> 6;
    const int b = blockIdx.z;
    const int m0 = blockIdx.y * BM;
    const int n0 = blockIdx.x * BN;
    const int wvm = (wv % WAVES_M) * WM * 16;
    const int wvn = (wv / WAVES_M) * WN * 16;

    const float* Ab = A + (size_t)m0 * K;
    const float* Bb = B + (size_t)b * K * SEQ + n0;

    float4v acc[WM][WN];
#pragma unroll
    for (int i = 0; i < WM; ++i)
#pragma unroll
        for (int j = 0; j < WN; ++j) acc[i][j] = (float4v){0.f, 0.f, 0.f, 0.f};

    for (int k0 = 0; k0 < K; k0 += BK) {
        __syncthreads();
#pragma unroll
        for (int q = t; q < BM * 8; q += 256) {
            int m = q >> 3, kq = (q & 7) * 4;
            float4v v = *(const float4v*)(Ab + (size_t)m * K + k0 + kq);
            short4v s4;
#pragma unroll
            for (int c = 0; c < 4; ++c) s4[c] = f2bf(v[c]);
            *(short4v*)&As[m * LP + kq] = s4;
        }
#pragma unroll
        for (int q = t; q < BN * 8; q += 256) {
            int n = q & (BN - 1), kq = (q >> 7) * 4;
            short4v s4;
#pragma unroll
            for (int c = 0; c < 4; ++c)
                s4[c] = f2bf(Bb[(size_t)(k0 + kq + c) * SEQ + n]);
            *(short4v*)&Bs[n * LP + kq] = s4;
        }
        __syncthreads();

        const int koff = (lane >> 4) * 8;
        short8 af[WM], bfr[WN];
#pragma unroll
        for (int i = 0; i < WM; ++i) {
            int m = wvm + i * 16 + (lane & 15);
            short4v lo = *(const short4v*)&As[m * LP + koff];
            short4v hi = *(const short4v*)&As[m * LP + koff + 4];
            af[i] = (short8){lo[0], lo[1], lo[2], lo[3], hi[0], hi[1], hi[2], hi[3]};
        }
#pragma unroll
        for (int j = 0; j < WN; ++j) {
            int n = wvn + j * 16 + (lane & 15);
            short4v lo = *(const short4v*)&Bs[n * LP + koff];
            short4v hi = *(const short4v*)&Bs[n * LP + koff + 4];
            bfr[j] = (short8){lo[0], lo[1], lo[2], lo[3], hi[0], hi[1], hi[2], hi[3]};
        }
#pragma unroll
        for (int i = 0; i < WM; ++i)
#pragma unroll
            for (int j = 0; j < WN; ++j)
                acc[i][j] = __builtin_amdgcn_mfma_f32_16x16x32_bf16(af[i], bfr[j],
                                                                    acc[i][j], 0, 0, 0);
    }

#pragma unroll
    for (int i = 0; i < WM; ++i)
#pragma unroll
        for (int r = 0; r < 4; ++r) {
            int m = m0 + wvm + i * 16 + (lane >> 4) * 4 + r;
            float bv = BIAS ? bias[m] : 0.f;
#pragma unroll
            for (int j = 0; j < WN; ++j) {
                int n = n0 + wvn + j * 16 + (lane & 15);
                C[((size_t)b * M + m) * SEQ + n] = acc[i][j][r] + bv;
            }
        }
}

// ---------------- K2: in-place RoPE (first 32 of d) + L2 norm along s ------
__global__ __launch_bounds__(256) void rope_norm(float* __restrict__ qkv) {
    __shared__ float red[512];
    const int t = threadIdx.x;
    const int bh = blockIdx.y;
    const int b = bh >> 3, h = bh & 7;
    const int z = blockIdx.z;
    float* base = qkv + ((size_t)b * OQKV + z * HID + h * DH) * SEQ;
    const int g = blockIdx.x;

    if (g < 16) {
        const int d = g;
        float* r1 = base + (size_t)d * SEQ;
        float* r2 = base + (size_t)(d + 16) * SEQ;
        const float invf = (float)pow(10000.0, -(double)d / 16.0);
        float n1[4], n2[4];
        float ss1 = 0.f, ss2 = 0.f;
#pragma unroll
        for (int r = 0; r < 4; ++r) {
            int s = t + 256 * r;
            float ang = (float)s * invf;
            float cs, sn;
            sincosf(ang, &sn, &cs);
            float a1 = r1[s], a2 = r2[s];
            n1[r] = a1 * cs - a2 * sn;
            n2[r] = a2 * cs + a1 * sn;
            ss1 += n1[r] * n1[r];
            ss2 += n2[r] * n2[r];
        }
        red[t] = ss1; red[256 + t] = ss2;
        __syncthreads();
        for (int ofs = 128; ofs > 0; ofs >>= 1) {
            if (t < ofs) { red[t] += red[t + ofs]; red[256 + t] += red[256 + t + ofs]; }
            __syncthreads();
        }
        float inv1 = 1.f / fmaxf(sqrtf(red[0]), 1e-12f);
        float inv2 = 1.f / fmaxf(sqrtf(red[256]), 1e-12f);
#pragma unroll
        for (int r = 0; r < 4; ++r) {
            int s = t + 256 * r;
            r1[s] = n1[r] * inv1;
            r2[s] = n2[r] * inv2;
        }
    } else {
        const int d = g + 16;
        float* r1 = base + (size_t)d * SEQ;
        float n1[4];
        float ss = 0.f;
#pragma unroll
        for (int r = 0; r < 4; ++r) {
            int s = t + 256 * r;
            n1[r] = r1[s];
            ss += n1[r] * n1[r];
        }
        red[t] = ss;
        __syncthreads();
        for (int ofs = 128; ofs > 0; ofs >>= 1) {
            if (t < ofs) red[t] += red[t + ofs];
            __syncthreads();
        }
        float inv1 = 1.f / fmaxf(sqrtf(red[0]), 1e-12f);
#pragma unroll
        for (int r = 0; r < 4; ++r) {
            int s = t + 256 * r;
            r1[s] = n1[r] * inv1;
        }
    }
}

// ---------------- K3: MFMA attention, 256 q-rows/block ----------------------
// Grid (4 i-blocks, 64 bh): K/V staged 4x per (b,h) instead of 16x.
// Wave owns 4 i-tiles of 16 rows; K/V fragments shared across the 4 tiles.
__global__ __launch_bounds__(256) void attn_mfma(const float* __restrict__ qkv,
                                                 float* __restrict__ ao) {
    __shared__ __align__(16) short kf[2][2][64][8];  // [jhalf][kstep][lane][e]
    __shared__ __align__(16) short vf[4][64][8];     // [dtile][lane][e]
    __shared__ __align__(16) short pt[4][16][72];    // per-wave P tile

    const int t = threadIdx.x;
    const int lane = t & 63, wv = t >> 6;
    const int bh = blockIdx.y, b = bh >> 3, h = bh & 7;
    const int i0 = blockIdx.x * 256;
    const float* qb = qkv + ((size_t)b * OQKV + h * DH) * SEQ;
    const float* kb = qb + (size_t)HID * SEQ;
    const float* vb = qb + (size_t)2 * HID * SEQ;

    // Q A-frags: 4 i-tiles per wave
    short8 aq[4][2];
#pragma unroll
    for (int it = 0; it < 4; ++it) {
        const int iq = i0 + wv * 64 + it * 16 + (lane & 15);
#pragma unroll
        for (int st = 0; st < 2; ++st)
#pragma unroll
            for (int e = 0; e < 8; ++e) {
                int d = st * 32 + (lane >> 4) * 8 + e;
                aq[it][st][e] = f2bf(qb[(size_t)d * SEQ + iq]);
            }
    }

    float4v acc[4][4];  // [it][dtile]
#pragma unroll
    for (int it = 0; it < 4; ++it)
#pragma unroll
        for (int dt = 0; dt < 4; ++dt) acc[it][dt] = (float4v){0.f, 0.f, 0.f, 0.f};
    float lsum[4][4];
#pragma unroll
    for (int it = 0; it < 4; ++it)
#pragma unroll
        for (int r = 0; r < 4; ++r) lsum[it][r] = 0.f;

    for (int jt = 0; jt < 32; ++jt) {
        __syncthreads();
        // ---- stage K,V tile (64 d x 32 j) into frag-ordered bf16 LDS ----
#pragma unroll
        for (int p = 0; p < 2; ++p) {
            int n = p * 256 + t;
            int d = n >> 3, jq = n & 7;
            float4v kv = *(const float4v*)(kb + (size_t)d * SEQ + jt * 32 + jq * 4);
#pragma unroll
            for (int c = 0; c < 4; ++c) {
                int jl = jq * 4 + c;
                kf[jl >> 4][d >> 5][((d >> 3) & 3) * 16 + (jl & 15)][d & 7] = f2bf(kv[c]);
            }
            float4v vv = *(const float4v*)(vb + (size_t)d * SEQ + jt * 32 + jq * 4);
            short4v vs;
#pragma unroll
            for (int c = 0; c < 4; ++c) vs[c] = f2bf(vv[c]);
            *(short4v*)&vf[d >> 4][(jq >> 1) * 16 + (d & 15)][(jq & 1) * 4] = vs;
        }
        __syncthreads();

        short8 bk00 = *(const short8*)&kf[0][0][lane][0];
        short8 bk01 = *(const short8*)&kf[0][1][lane][0];
        short8 bk10 = *(const short8*)&kf[1][0][lane][0];
        short8 bk11 = *(const short8*)&kf[1][1][lane][0];
        short8 bv0 = *(const short8*)&vf[0][lane][0];
        short8 bv1 = *(const short8*)&vf[1][lane][0];
        short8 bv2 = *(const short8*)&vf[2][lane][0];
        short8 bv3 = *(const short8*)&vf[3][lane][0];

#pragma unroll
        for (int it = 0; it < 4; ++it) {
            float4v s0 = (float4v){0.f, 0.f, 0.f, 0.f};
            float4v s1 = (float4v){0.f, 0.f, 0.f, 0.f};
            s0 = __builtin_amdgcn_mfma_f32_16x16x32_bf16(aq[it][0], bk00, s0, 0, 0, 0);
            s0 = __builtin_amdgcn_mfma_f32_16x16x32_bf16(aq[it][1], bk01, s0, 0, 0, 0);
            s1 = __builtin_amdgcn_mfma_f32_16x16x32_bf16(aq[it][0], bk10, s1, 0, 0, 0);
            s1 = __builtin_amdgcn_mfma_f32_16x16x32_bf16(aq[it][1], bk11, s1, 0, 0, 0);

#pragma unroll
            for (int r = 0; r < 4; ++r) {
                float p0 = __expf(10.f * s0[r]);   // native v_exp; |10*s| small
                short pb0 = f2bf(p0);
                lsum[it][r] += bf2f(pb0);
                pt[wv][(lane >> 4) * 4 + r][lane & 15] = pb0;
                float p1 = __expf(10.f * s1[r]);
                short pb1 = f2bf(p1);
                lsum[it][r] += bf2f(pb1);
                pt[wv][(lane >> 4) * 4 + r][16 + (lane & 15)] = pb1;
            }
            // wave-private tile; DS ops are in-order within a wave
            short8 ap = *(const short8*)&pt[wv][lane & 15][(lane >> 4) * 8];

            acc[it][0] = __builtin_amdgcn_mfma_f32_16x16x32_bf16(ap, bv0, acc[it][0], 0, 0, 0);
            acc[it][1] = __builtin_amdgcn_mfma_f32_16x16x32_bf16(ap, bv1, acc[it][1], 0, 0, 0);
            acc[it][2] = __builtin_amdgcn_mfma_f32_16x16x32_bf16(ap, bv2, acc[it][2], 0, 0, 0);
            acc[it][3] = __builtin_amdgcn_mfma_f32_16x16x32_bf16(ap, bv3, acc[it][3], 0, 0, 0);
        }
    }

#pragma unroll
    for (int it = 0; it < 4; ++it)
#pragma unroll
        for (int r = 0; r < 4; ++r) {
            float v = lsum[it][r];
#pragma unroll
            for (int o = 1; o < 16; o <<= 1) v += __shfl_xor(v, o, 64);
            lsum[it][r] = v;
        }

    float* aob = ao + ((size_t)b * HID + h * DH) * SEQ;
#pragma unroll
    for (int it = 0; it < 4; ++it)
#pragma unroll
        for (int dt = 0; dt < 4; ++dt)
#pragma unroll
            for (int r = 0; r < 4; ++r) {
                int d = dt * 16 + (lane & 15);
                int s = i0 + wv * 64 + it * 16 + (lane >> 4) * 4 + r;
                aob[(size_t)d * SEQ + s] = acc[it][dt][r] / lsum[it][r];
            }
}

extern "C" void kernel_launch(void* const* d_in, const int* in_sizes, int n_in,
                              void* d_out, int out_size, void* d_ws, size_t ws_size,
                              hipStream_t stream) {
    const float* x = (const float*)d_in[0];
    const float* w_qkv = (const float*)d_in[1];
    const float* w_out = (const float*)d_in[2];
    const float* b_out = (const float*)d_in[3];
    float* out = (float*)d_out;

    float* qkv = (float*)d_ws;                   // 8*1536*1024 f = 50.3 MB
    float* ao = qkv + (size_t)NB * OQKV * SEQ;   // 8*512*1024 f  = 16.8 MB

    gemm_mfma<128, 2, 4, 4, false><<<dim3(8, 12, 8), 256, 0, stream>>>(
        w_qkv, x, nullptr, qkv, OQKV, CIN);
    rope_norm<<<dim3(48, 64, 2), 256, 0, stream>>>(qkv);
    attn_mfma<<<dim3(4, 64), 256, 0, stream>>>(qkv, ao);
    gemm_mfma<64, 1, 4, 2, true><<<dim3(8, 4, 8), 256, 0, stream>>>(
        w_out, ao, b_out, out, CIN, HID);
}

// Round 5
// 216.186 us; speedup vs baseline: 1.1580x; 1.1580x over previous
//
#include <hip/hip_runtime.h>
#include <math.h>

#define NB 8
#define CIN 256
#define SEQ 1024
#define NH 8
#define DH 64
#define HID 512
#define OQKV 1536

typedef __attribute__((ext_vector_type(8))) short short8;
typedef __attribute__((ext_vector_type(4))) short short4v;
typedef __attribute__((ext_vector_type(4))) float float4v;

static __device__ inline short f2bf(float x) {  // RNE
    union { float f; unsigned u; } c; c.f = x;
    unsigned r = (c.u + 0x7FFFu + ((c.u >> 16) & 1u)) >> 16;
    return (short)r;
}

// ============ MFMA GEMM (unchanged, verified) ==============================
#define BN 128
#define BK 32
#define LP 36

template<int BM, int WAVES_M, int WM, int WN, bool BIAS>
__global__ __launch_bounds__(256) void gemm_mfma(const float* __restrict__ A,
                                                 const float* __restrict__ B,
                                                 const float* __restrict__ bias,
                                                 float* __restrict__ C,
                                                 int M, int K) {
    __shared__ __align__(16) short As[BM * LP];
    __shared__ __align__(16) short Bs[BN * LP];
    const int t = threadIdx.x;
    const int lane = t & 63, wv = t >> 6;
    const int b = blockIdx.z;
    const int m0 = blockIdx.y * BM;
    const int n0 = blockIdx.x * BN;
    const int wvm = (wv % WAVES_M) * WM * 16;
    const int wvn = (wv / WAVES_M) * WN * 16;

    const float* Ab = A + (size_t)m0 * K;
    const float* Bb = B + (size_t)b * K * SEQ + n0;

    float4v acc[WM][WN];
#pragma unroll
    for (int i = 0; i < WM; ++i)
#pragma unroll
        for (int j = 0; j < WN; ++j) acc[i][j] = (float4v){0.f, 0.f, 0.f, 0.f};

    for (int k0 = 0; k0 < K; k0 += BK) {
        __syncthreads();
#pragma unroll
        for (int q = t; q < BM * 8; q += 256) {
            int m = q >> 3, kq = (q & 7) * 4;
            float4v v = *(const float4v*)(Ab + (size_t)m * K + k0 + kq);
            short4v s4;
#pragma unroll
            for (int c = 0; c < 4; ++c) s4[c] = f2bf(v[c]);
            *(short4v*)&As[m * LP + kq] = s4;
        }
#pragma unroll
        for (int q = t; q < BN * 8; q += 256) {
            int n = q & (BN - 1), kq = (q >> 7) * 4;
            short4v s4;
#pragma unroll
            for (int c = 0; c < 4; ++c)
                s4[c] = f2bf(Bb[(size_t)(k0 + kq + c) * SEQ + n]);
            *(short4v*)&Bs[n * LP + kq] = s4;
        }
        __syncthreads();

        const int koff = (lane >> 4) * 8;
        short8 af[WM], bfr[WN];
#pragma unroll
        for (int i = 0; i < WM; ++i) {
            int m = wvm + i * 16 + (lane & 15);
            short4v lo = *(const short4v*)&As[m * LP + koff];
            short4v hi = *(const short4v*)&As[m * LP + koff + 4];
            af[i] = (short8){lo[0], lo[1], lo[2], lo[3], hi[0], hi[1], hi[2], hi[3]};
        }
#pragma unroll
        for (int j = 0; j < WN; ++j) {
            int n = wvn + j * 16 + (lane & 15);
            short4v lo = *(const short4v*)&Bs[n * LP + koff];
            short4v hi = *(const short4v*)&Bs[n * LP + koff + 4];
            bfr[j] = (short8){lo[0], lo[1], lo[2], lo[3], hi[0], hi[1], hi[2], hi[3]};
        }
#pragma unroll
        for (int i = 0; i < WM; ++i)
#pragma unroll
            for (int j = 0; j < WN; ++j)
                acc[i][j] = __builtin_amdgcn_mfma_f32_16x16x32_bf16(af[i], bfr[j],
                                                                    acc[i][j], 0, 0, 0);
    }

#pragma unroll
    for (int i = 0; i < WM; ++i)
#pragma unroll
        for (int r = 0; r < 4; ++r) {
            int m = m0 + wvm + i * 16 + (lane >> 4) * 4 + r;
            float bv = BIAS ? bias[m] : 0.f;
#pragma unroll
            for (int j = 0; j < WN; ++j) {
                int n = n0 + wvn + j * 16 + (lane & 15);
                C[((size_t)b * M + m) * SEQ + n] = acc[i][j][r] + bv;
            }
        }
}

// ---------------- K2: RoPE + L2 norm, wave-per-row, no barriers -------------
// grid (12, 64, 2): wave-task tid = bx*4+wv; tid<16 -> rotated pair (d,d+16);
// else single row d = tid+16. 16 s-elements per lane (lane*16..+15).
__global__ __launch_bounds__(256) void rope_norm(float* __restrict__ qkv) {
    const int t = threadIdx.x, lane = t & 63, wv = t >> 6;
    const int bh = blockIdx.y, b = bh >> 3, h = bh & 7;
    const int z = blockIdx.z;
    float* base = qkv + ((size_t)b * OQKV + z * HID + h * DH) * SEQ;
    const int tid = blockIdx.x * 4 + wv;

    if (tid < 16) {
        const int d = tid;
        float* r1 = base + (size_t)d * SEQ;
        float* r2 = base + (size_t)(d + 16) * SEQ;
        const float invf = exp2f(-(float)d * 0.83048202372184045f);  // 10000^(-d/16)
        float4v A1[4], A2[4];
#pragma unroll
        for (int q4 = 0; q4 < 4; ++q4) {
            A1[q4] = *(const float4v*)(r1 + lane * 16 + q4 * 4);
            A2[q4] = *(const float4v*)(r2 + lane * 16 + q4 * 4);
        }
        float ss1 = 0.f, ss2 = 0.f;
#pragma unroll
        for (int q4 = 0; q4 < 4; ++q4)
#pragma unroll
            for (int e = 0; e < 4; ++e) {
                float ang = (float)(lane * 16 + q4 * 4 + e) * invf;
                float sn, cs;
                __sincosf(ang, &sn, &cs);
                float a1 = A1[q4][e], a2 = A2[q4][e];
                float n1 = a1 * cs - a2 * sn;
                float n2 = a2 * cs + a1 * sn;
                A1[q4][e] = n1; A2[q4][e] = n2;
                ss1 += n1 * n1; ss2 += n2 * n2;
            }
#pragma unroll
        for (int o = 1; o < 64; o <<= 1) {
            ss1 += __shfl_xor(ss1, o, 64);
            ss2 += __shfl_xor(ss2, o, 64);
        }
        float inv1 = 1.f / fmaxf(sqrtf(ss1), 1e-12f);
        float inv2 = 1.f / fmaxf(sqrtf(ss2), 1e-12f);
#pragma unroll
        for (int q4 = 0; q4 < 4; ++q4) {
            float4v o1, o2;
#pragma unroll
            for (int e = 0; e < 4; ++e) { o1[e] = A1[q4][e] * inv1; o2[e] = A2[q4][e] * inv2; }
            *(float4v*)(r1 + lane * 16 + q4 * 4) = o1;
            *(float4v*)(r2 + lane * 16 + q4 * 4) = o2;
        }
    } else {
        const int d = tid + 16;
        float* r1 = base + (size_t)d * SEQ;
        float4v A1[4];
        float ss = 0.f;
#pragma unroll
        for (int q4 = 0; q4 < 4; ++q4) {
            A1[q4] = *(const float4v*)(r1 + lane * 16 + q4 * 4);
#pragma unroll
            for (int e = 0; e < 4; ++e) ss += A1[q4][e] * A1[q4][e];
        }
#pragma unroll
        for (int o = 1; o < 64; o <<= 1) ss += __shfl_xor(ss, o, 64);
        float inv1 = 1.f / fmaxf(sqrtf(ss), 1e-12f);
#pragma unroll
        for (int q4 = 0; q4 < 4; ++q4) {
            float4v o1;
#pragma unroll
            for (int e = 0; e < 4; ++e) o1[e] = A1[q4][e] * inv1;
            *(float4v*)(r1 + lane * 16 + q4 * 4) = o1;
        }
    }
}

// ---------------- K3: pack Q/K/V into frag-ordered bf16 ---------------------
// Q/K frag (slice,st): row = slice*16+(lane&15), d = st*32+(lane>>4)*8+e.
// V frag (jt,dt):      d = dt*16+(lane&15),      j = jt*32+(lane>>4)*8+e.
// Q pre-scaled by SCALE=10 (folds softmax scale into the QK MFMA).
__global__ __launch_bounds__(256) void pack_frags(const float* __restrict__ qkv,
                                                  short* __restrict__ qp,
                                                  short* __restrict__ kp,
                                                  short* __restrict__ vp) {
    const int t = threadIdx.x, lane = t & 63, wv = t >> 6;
    const int bh = blockIdx.y, b = bh >> 3, h = bh & 7;
    const int fid = blockIdx.x * 4 + wv;  // 0..383
    const float* base = qkv + ((size_t)b * OQKV + h * DH) * SEQ;
    const int c = lane & 15, q = lane >> 4;

    if (fid < 256) {
        const int z = fid >> 7;          // 0=Q, 1=K
        const int r = fid & 127;
        const int slice = r >> 1, st = r & 1;
        const float* src = base + (size_t)z * HID * SEQ;
        const float scale = z ? 1.f : 10.f;
        const int row = slice * 16 + c;
        const int d0 = st * 32 + q * 8;
        short8 v;
#pragma unroll
        for (int e = 0; e < 8; ++e)
            v[e] = f2bf(src[(size_t)(d0 + e) * SEQ + row] * scale);
        short* dst = (z ? kp : qp) + ((((size_t)bh * 64 + slice) * 2 + st) * 64 + lane) * 8;
        *(short8*)dst = v;
    } else {
        const int r = fid - 256;
        const int jt = r >> 2, dt = r & 3;
        const float* src = base + (size_t)2 * HID * SEQ;
        const int d = dt * 16 + c;
        const float* p = src + (size_t)d * SEQ + jt * 32 + q * 8;
        float4v lo = *(const float4v*)p;
        float4v hi = *(const float4v*)(p + 4);
        short8 v;
#pragma unroll
        for (int e = 0; e < 4; ++e) { v[e] = f2bf(lo[e]); v[4 + e] = f2bf(hi[e]); }
        short* dst = vp + ((((size_t)bh * 32 + jt) * 4 + dt) * 64 + lane) * 8;
        *(short8*)dst = v;
    }
}

// ---------------- K4: attention, no barriers, pre-packed frags --------------
// Wave owns i-tile (16 q-rows). Computes S^T = K.Q^T so the C-layout's
// col=lane&15 axis is i, making the P relayout 4 packed b32 writes + 1 b128
// read. Softmax denominator via MFMA against a ones-fragment.
__global__ __launch_bounds__(256) void attn_mfma(const short* __restrict__ qp,
                                                 const short* __restrict__ kp,
                                                 const short* __restrict__ vp,
                                                 float* __restrict__ ao) {
    __shared__ __align__(16) short pt[4][16][40];  // pitch 80B (16B-aligned rows)
    const int t = threadIdx.x, lane = t & 63, wv = t >> 6;
    const int bh = blockIdx.y;
    const int it = blockIdx.x * 4 + wv;  // 0..63
    const int c = lane & 15, q = lane >> 4;

    const short* qpb = qp + (((size_t)bh * 64 + it) * 2 * 64 + lane) * 8;
    short8 aq0 = *(const short8*)qpb;
    short8 aq1 = *(const short8*)(qpb + 512);

    short8 ones;
#pragma unroll
    for (int e = 0; e < 8; ++e) ones[e] = (short)0x3F80;  // bf16(1.0)

    float4v acc[4];
#pragma unroll
    for (int dt = 0; dt < 4; ++dt) acc[dt] = (float4v){0.f, 0.f, 0.f, 0.f};
    float4v accS = (float4v){0.f, 0.f, 0.f, 0.f};

    for (int jt = 0; jt < 32; ++jt) {
        const short* kbb = kp + (((size_t)bh * 64 + jt * 2) * 2 * 64 + lane) * 8;
        short8 bk00 = *(const short8*)kbb;              // jhalf0, d 0..31
        short8 bk01 = *(const short8*)(kbb + 512);      // jhalf0, d 32..63
        short8 bk10 = *(const short8*)(kbb + 1024);     // jhalf1, d 0..31
        short8 bk11 = *(const short8*)(kbb + 1536);
        const short* vbb = vp + (((size_t)bh * 32 + jt) * 4 * 64 + lane) * 8;
        short8 bv0 = *(const short8*)vbb;
        short8 bv1 = *(const short8*)(vbb + 512);
        short8 bv2 = *(const short8*)(vbb + 1024);
        short8 bv3 = *(const short8*)(vbb + 1536);

        // S^T tiles: rows j, cols i (Q prescaled by 10)
        float4v s0 = (float4v){0.f, 0.f, 0.f, 0.f};
        float4v s1 = (float4v){0.f, 0.f, 0.f, 0.f};
        s0 = __builtin_amdgcn_mfma_f32_16x16x32_bf16(bk00, aq0, s0, 0, 0, 0);
        s0 = __builtin_amdgcn_mfma_f32_16x16x32_bf16(bk01, aq1, s0, 0, 0, 0);
        s1 = __builtin_amdgcn_mfma_f32_16x16x32_bf16(bk10, aq0, s1, 0, 0, 0);
        s1 = __builtin_amdgcn_mfma_f32_16x16x32_bf16(bk11, aq1, s1, 0, 0, 0);

        // P^T = exp(S^T), truncate to bf16, pack pairs, store to [i][j] tile
        int* ptw = (int*)&pt[wv][c][0];  // 20 ints per row
#pragma unroll
        for (int jh = 0; jh < 2; ++jh) {
            float4v s = jh ? s1 : s0;
            unsigned u0 = __float_as_uint(__expf(s[0]));
            unsigned u1 = __float_as_uint(__expf(s[1]));
            unsigned u2 = __float_as_uint(__expf(s[2]));
            unsigned u3 = __float_as_uint(__expf(s[3]));
            ptw[jh * 8 + q * 2]     = (int)((u1 & 0xFFFF0000u) | (u0 >> 16));
            ptw[jh * 8 + q * 2 + 1] = (int)((u3 & 0xFFFF0000u) | (u2 >> 16));
        }
        short8 ap = *(const short8*)&pt[wv][c][q * 8];  // A-frag: m=i, k=j

        acc[0] = __builtin_amdgcn_mfma_f32_16x16x32_bf16(ap, bv0, acc[0], 0, 0, 0);
        acc[1] = __builtin_amdgcn_mfma_f32_16x16x32_bf16(ap, bv1, acc[1], 0, 0, 0);
        acc[2] = __builtin_amdgcn_mfma_f32_16x16x32_bf16(ap, bv2, acc[2], 0, 0, 0);
        acc[3] = __builtin_amdgcn_mfma_f32_16x16x32_bf16(ap, bv3, acc[3], 0, 0, 0);
        accS   = __builtin_amdgcn_mfma_f32_16x16x32_bf16(ap, ones, accS, 0, 0, 0);
    }

    float inv[4];
#pragma unroll
    for (int r = 0; r < 4; ++r) inv[r] = 1.0f / accS[r];

    float* aob = ao + (size_t)bh * 64 * SEQ;  // b*HID + h*DH == 64*bh
#pragma unroll
    for (int dt = 0; dt < 4; ++dt)
#pragma unroll
        for (int r = 0; r < 4; ++r)
            aob[(size_t)(dt * 16 + c) * SEQ + it * 16 + q * 4 + r] = acc[dt][r] * inv[r];
}

extern "C" void kernel_launch(void* const* d_in, const int* in_sizes, int n_in,
                              void* d_out, int out_size, void* d_ws, size_t ws_size,
                              hipStream_t stream) {
    const float* x = (const float*)d_in[0];
    const float* w_qkv = (const float*)d_in[1];
    const float* w_out = (const float*)d_in[2];
    const float* b_out = (const float*)d_in[3];
    float* out = (float*)d_out;

    char* w = (char*)d_ws;
    float* qkv = (float*)w;                                  // 50.33 MB
    float* ao  = (float*)(w + 50331648);                     // 16.78 MB
    short* qp  = (short*)(w + 50331648 + 16777216);          // 8.39 MB
    short* kp  = (short*)(w + 50331648 + 16777216 + 8388608);
    short* vp  = (short*)(w + 50331648 + 16777216 + 2 * 8388608);
    // total 92.3 MB

    gemm_mfma<128, 2, 4, 4, false><<<dim3(8, 12, 8), 256, 0, stream>>>(
        w_qkv, x, nullptr, qkv, OQKV, CIN);
    rope_norm<<<dim3(12, 64, 2), 256, 0, stream>>>(qkv);
    pack_frags<<<dim3(96, 64), 256, 0, stream>>>(qkv, qp, kp, vp);
    attn_mfma<<<dim3(16, 64), 256, 0, stream>>>(qp, kp, vp, ao);
    gemm_mfma<64, 1, 4, 2, true><<<dim3(8, 4, 8), 256, 0, stream>>>(
        w_out, ao, b_out, out, CIN, HID);
}

// Round 6
// 201.295 us; speedup vs baseline: 1.2437x; 1.0740x over previous
//
#include <hip/hip_runtime.h>
#include <math.h>

#define NB 8
#define CIN 256
#define SEQ 1024
#define NH 8
#define DH 64
#define HID 512
#define OQKV 1536

typedef __attribute__((ext_vector_type(8))) short short8;
typedef __attribute__((ext_vector_type(4))) short short4v;
typedef __attribute__((ext_vector_type(4))) float float4v;

static __device__ inline short f2bf(float x) {  // RNE
    union { float f; unsigned u; } c; c.f = x;
    unsigned r = (c.u + 0x7FFFu + ((c.u >> 16) & 1u)) >> 16;
    return (short)r;
}

// ============ K1: MFMA GEMM for qkv projection (verified template) =========
#define BN 128
#define BK 32
#define LP 36

template<int BM, int WAVES_M, int WM, int WN>
__global__ __launch_bounds__(256) void gemm_mfma(const float* __restrict__ A,
                                                 const float* __restrict__ B,
                                                 float* __restrict__ C,
                                                 int M, int K) {
    __shared__ __align__(16) short As[BM * LP];
    __shared__ __align__(16) short Bs[BN * LP];
    const int t = threadIdx.x;
    const int lane = t & 63, wv = t >> 6;
    const int b = blockIdx.z;
    const int m0 = blockIdx.y * BM;
    const int n0 = blockIdx.x * BN;
    const int wvm = (wv % WAVES_M) * WM * 16;
    const int wvn = (wv / WAVES_M) * WN * 16;

    const float* Ab = A + (size_t)m0 * K;
    const float* Bb = B + (size_t)b * K * SEQ + n0;

    float4v acc[WM][WN];
#pragma unroll
    for (int i = 0; i < WM; ++i)
#pragma unroll
        for (int j = 0; j < WN; ++j) acc[i][j] = (float4v){0.f, 0.f, 0.f, 0.f};

    for (int k0 = 0; k0 < K; k0 += BK) {
        __syncthreads();
#pragma unroll
        for (int qq = t; qq < BM * 8; qq += 256) {
            int m = qq >> 3, kq = (qq & 7) * 4;
            float4v v = *(const float4v*)(Ab + (size_t)m * K + k0 + kq);
            short4v s4;
#pragma unroll
            for (int cc = 0; cc < 4; ++cc) s4[cc] = f2bf(v[cc]);
            *(short4v*)&As[m * LP + kq] = s4;
        }
#pragma unroll
        for (int qq = t; qq < BN * 8; qq += 256) {
            int n = qq & (BN - 1), kq = (qq >> 7) * 4;
            short4v s4;
#pragma unroll
            for (int cc = 0; cc < 4; ++cc)
                s4[cc] = f2bf(Bb[(size_t)(k0 + kq + cc) * SEQ + n]);
            *(short4v*)&Bs[n * LP + kq] = s4;
        }
        __syncthreads();

        const int koff = (lane >> 4) * 8;
        short8 af[WM], bfr[WN];
#pragma unroll
        for (int i = 0; i < WM; ++i) {
            int m = wvm + i * 16 + (lane & 15);
            short4v lo = *(const short4v*)&As[m * LP + koff];
            short4v hi = *(const short4v*)&As[m * LP + koff + 4];
            af[i] = (short8){lo[0], lo[1], lo[2], lo[3], hi[0], hi[1], hi[2], hi[3]};
        }
#pragma unroll
        for (int j = 0; j < WN; ++j) {
            int n = wvn + j * 16 + (lane & 15);
            short4v lo = *(const short4v*)&Bs[n * LP + koff];
            short4v hi = *(const short4v*)&Bs[n * LP + koff + 4];
            bfr[j] = (short8){lo[0], lo[1], lo[2], lo[3], hi[0], hi[1], hi[2], hi[3]};
        }
#pragma unroll
        for (int i = 0; i < WM; ++i)
#pragma unroll
            for (int j = 0; j < WN; ++j)
                acc[i][j] = __builtin_amdgcn_mfma_f32_16x16x32_bf16(af[i], bfr[j],
                                                                    acc[i][j], 0, 0, 0);
    }

#pragma unroll
    for (int i = 0; i < WM; ++i)
#pragma unroll
        for (int r = 0; r < 4; ++r) {
            int m = m0 + wvm + i * 16 + (lane >> 4) * 4 + r;
#pragma unroll
            for (int j = 0; j < WN; ++j) {
                int n = n0 + wvn + j * 16 + (lane & 15);
                C[((size_t)b * M + m) * SEQ + n] = acc[i][j][r];
            }
        }
}

// ============ K2: fused RoPE + L2norm + frag-pack (wave per 2 rows) =========
// grid (8, 64 bh, 3 z). z=0: q (rope+norm+pack, x10), z=1: k, z=2: v (pack).
// Lane owns 16 consecutive s (= one 16-row frag slice for q/k).
__global__ __launch_bounds__(256) void rope_pack(const float* __restrict__ qkv,
                                                 short* __restrict__ qp,
                                                 short* __restrict__ kp,
                                                 short* __restrict__ vp) {
    const int t = threadIdx.x, lane = t & 63, wv = t >> 6;
    const int bh = blockIdx.y, b = bh >> 3, h = bh & 7;
    const int z = blockIdx.z;
    const int tid = blockIdx.x * 4 + wv;  // 0..31
    const float* base = qkv + ((size_t)b * OQKV + z * HID + h * DH) * SEQ;

    if (z < 2) {
        short* dst = (z ? kp : qp) + (size_t)bh * 65536;
        const float scale = z ? 1.f : 10.f;  // fold softmax scale into Q
        const bool rot = tid < 16;
        const int d1 = rot ? tid : tid + 16;
        const int d2 = rot ? tid + 16 : tid + 32;
        const float* r1 = base + (size_t)d1 * SEQ + lane * 16;
        const float* r2 = base + (size_t)d2 * SEQ + lane * 16;
        float4v A1[4], A2[4];
#pragma unroll
        for (int q4 = 0; q4 < 4; ++q4) {
            A1[q4] = *(const float4v*)(r1 + q4 * 4);
            A2[q4] = *(const float4v*)(r2 + q4 * 4);
        }
        if (rot) {
            const float invf = exp2f(-(float)d1 * 0.83048202372184045f);  // 10000^(-d/16)
#pragma unroll
            for (int q4 = 0; q4 < 4; ++q4)
#pragma unroll
                for (int e = 0; e < 4; ++e) {
                    float ang = (float)(lane * 16 + q4 * 4 + e) * invf;
                    float sn, cs;
                    __sincosf(ang, &sn, &cs);
                    float a1 = A1[q4][e], a2 = A2[q4][e];
                    A1[q4][e] = a1 * cs - a2 * sn;
                    A2[q4][e] = a2 * cs + a1 * sn;
                }
        }
        float ss1 = 0.f, ss2 = 0.f;
#pragma unroll
        for (int q4 = 0; q4 < 4; ++q4)
#pragma unroll
            for (int e = 0; e < 4; ++e) {
                ss1 += A1[q4][e] * A1[q4][e];
                ss2 += A2[q4][e] * A2[q4][e];
            }
#pragma unroll
        for (int o = 1; o < 64; o <<= 1) {
            ss1 += __shfl_xor(ss1, o, 64);
            ss2 += __shfl_xor(ss2, o, 64);
        }
        const float i1 = scale / fmaxf(sqrtf(ss1), 1e-12f);
        const float i2 = scale / fmaxf(sqrtf(ss2), 1e-12f);
        // pack: frag element (row=s, d): slice=s>>4 (=lane), c=s&15, st=d>>5,
        // qpart=(d>>3)&3, e=d&7 -> dst[((slice*2+st)*64 + qpart*16 + c)*8 + e]
        {
            const int st = d1 >> 5, qp_ = (d1 >> 3) & 3, e = d1 & 7;
            short* p = dst + (((size_t)lane * 2 + st) * 64 + qp_ * 16) * 8 + e;
#pragma unroll
            for (int k = 0; k < 16; ++k) p[k * 8] = f2bf(A1[k >> 2][k & 3] * i1);
        }
        {
            const int st = d2 >> 5, qp_ = (d2 >> 3) & 3, e = d2 & 7;
            short* p = dst + (((size_t)lane * 2 + st) * 64 + qp_ * 16) * 8 + e;
#pragma unroll
            for (int k = 0; k < 16; ++k) p[k * 8] = f2bf(A2[k >> 2][k & 3] * i2);
        }
    } else {
        // V: frag element (d, j): jt=j>>5, dt=d>>4, c=d&15, qpart=(j>>3)&3, e=j&7
        // lane's 16 j are contiguous -> two contiguous short8 stores
        short* dst = vp + (size_t)bh * 65536;
#pragma unroll
        for (int rr = 0; rr < 2; ++rr) {
            const int d = tid + rr * 32;
            const float* r1 = base + (size_t)d * SEQ + lane * 16;
            const int dt = d >> 4, cc = d & 15;
            const int jt = lane >> 1, q0 = (lane & 1) * 2;
            short8 s0, s1;
#pragma unroll
            for (int q4 = 0; q4 < 4; ++q4) {
                float4v v = *(const float4v*)(r1 + q4 * 4);
#pragma unroll
                for (int e = 0; e < 4; ++e) {
                    short sv = f2bf(v[e]);
                    if (q4 < 2) s0[q4 * 4 + e] = sv;
                    else s1[(q4 - 2) * 4 + e] = sv;
                }
            }
            short* p0 = dst + (((size_t)jt * 4 + dt) * 64 + q0 * 16 + cc) * 8;
            *(short8*)p0 = s0;
            *(short8*)(p0 + 128) = s1;  // qpart+1 => +16 lanes = +128 shorts
        }
    }
}

// ============ K3: pack w_out into A-frag order bf16 (runs once, tiny) =======
// wp[mt*16+kt][lane][e]: m = mt*16 + (lane&15), k = kt*32 + (lane>>4)*8 + e
__global__ __launch_bounds__(256) void pack_w(const float* __restrict__ w_out,
                                              short* __restrict__ wp) {
    const int t = threadIdx.x, lane = t & 63, wv = t >> 6;
    const int fid = blockIdx.x * 4 + wv;  // 0..255: mt = fid>>4, kt = fid&15
    const int m = (fid >> 4) * 16 + (lane & 15);
    const int k0 = (fid & 15) * 32 + (lane >> 4) * 8;
    const float* p = w_out + (size_t)m * HID + k0;
    float4v lo = *(const float4v*)p;
    float4v hi = *(const float4v*)(p + 4);
    short8 v;
#pragma unroll
    for (int e = 0; e < 4; ++e) { v[e] = f2bf(lo[e]); v[4 + e] = f2bf(hi[e]); }
    *(short8*)(wp + (size_t)fid * 512 + lane * 8) = v;
}

// ============ K4: attention (barrier-free), scatters bf16 B-frag output =====
__global__ __launch_bounds__(256) void attn_mfma(const short* __restrict__ qp,
                                                 const short* __restrict__ kp,
                                                 const short* __restrict__ vp,
                                                 short* __restrict__ aop) {
    __shared__ __align__(16) short pt[4][16][40];  // per-wave P tile, 80B pitch
    const int t = threadIdx.x, lane = t & 63, wv = t >> 6;
    const int bh = blockIdx.y, b = bh >> 3, h = bh & 7;
    const int it = blockIdx.x * 4 + wv;  // 0..63
    const int c = lane & 15, q = lane >> 4;

    const short* qpb = qp + (((size_t)bh * 64 + it) * 2 * 64 + lane) * 8;
    short8 aq0 = *(const short8*)qpb;
    short8 aq1 = *(const short8*)(qpb + 512);

    short8 ones;
#pragma unroll
    for (int e = 0; e < 8; ++e) ones[e] = (short)0x3F80;  // bf16(1.0)

    float4v acc[4];
#pragma unroll
    for (int dt = 0; dt < 4; ++dt) acc[dt] = (float4v){0.f, 0.f, 0.f, 0.f};
    float4v accS = (float4v){0.f, 0.f, 0.f, 0.f};

    for (int jt = 0; jt < 32; ++jt) {
        const short* kbb = kp + (((size_t)bh * 64 + jt * 2) * 2 * 64 + lane) * 8;
        short8 bk00 = *(const short8*)kbb;
        short8 bk01 = *(const short8*)(kbb + 512);
        short8 bk10 = *(const short8*)(kbb + 1024);
        short8 bk11 = *(const short8*)(kbb + 1536);
        const short* vbb = vp + (((size_t)bh * 32 + jt) * 4 * 64 + lane) * 8;
        short8 bv0 = *(const short8*)vbb;
        short8 bv1 = *(const short8*)(vbb + 512);
        short8 bv2 = *(const short8*)(vbb + 1024);
        short8 bv3 = *(const short8*)(vbb + 1536);

        // S^T = K.Q^T (Q prescaled by 10): C-layout col axis = i
        float4v s0 = (float4v){0.f, 0.f, 0.f, 0.f};
        float4v s1 = (float4v){0.f, 0.f, 0.f, 0.f};
        s0 = __builtin_amdgcn_mfma_f32_16x16x32_bf16(bk00, aq0, s0, 0, 0, 0);
        s0 = __builtin_amdgcn_mfma_f32_16x16x32_bf16(bk01, aq1, s0, 0, 0, 0);
        s1 = __builtin_amdgcn_mfma_f32_16x16x32_bf16(bk10, aq0, s1, 0, 0, 0);
        s1 = __builtin_amdgcn_mfma_f32_16x16x32_bf16(bk11, aq1, s1, 0, 0, 0);

        // P^T = exp(S^T) -> truncate to bf16 pairs -> per-wave LDS tile
        int* ptw = (int*)&pt[wv][c][0];
#pragma unroll
        for (int jh = 0; jh < 2; ++jh) {
            float4v s = jh ? s1 : s0;
            unsigned u0 = __float_as_uint(__expf(s[0]));
            unsigned u1 = __float_as_uint(__expf(s[1]));
            unsigned u2 = __float_as_uint(__expf(s[2]));
            unsigned u3 = __float_as_uint(__expf(s[3]));
            ptw[jh * 8 + q * 2]     = (int)((u1 & 0xFFFF0000u) | (u0 >> 16));
            ptw[jh * 8 + q * 2 + 1] = (int)((u3 & 0xFFFF0000u) | (u2 >> 16));
        }
        short8 ap = *(const short8*)&pt[wv][c][q * 8];  // A-frag: m=i, k=j

        acc[0] = __builtin_amdgcn_mfma_f32_16x16x32_bf16(ap, bv0, acc[0], 0, 0, 0);
        acc[1] = __builtin_amdgcn_mfma_f32_16x16x32_bf16(ap, bv1, acc[1], 0, 0, 0);
        acc[2] = __builtin_amdgcn_mfma_f32_16x16x32_bf16(ap, bv2, acc[2], 0, 0, 0);
        acc[3] = __builtin_amdgcn_mfma_f32_16x16x32_bf16(ap, bv3, acc[3], 0, 0, 0);
        accS   = __builtin_amdgcn_mfma_f32_16x16x32_bf16(ap, ones, accS, 0, 0, 0);
    }

    float inv[4];
#pragma unroll
    for (int r = 0; r < 4; ++r) inv[r] = 1.0f / accS[r];

    // scatter bf16 output directly into out_proj B-frag order:
    // element (ch = h*64 + dt*16 + c, s = it*16 + q*4 + r) ->
    // aop[b][kt=ch>>5][nt=it][lane'=(s&15)|(((ch>>3)&3)<<4)][e=ch&7]
    short* ab = aop + (size_t)b * 524288;
#pragma unroll
    for (int dt = 0; dt < 4; ++dt) {
        const int kt = h * 2 + (dt >> 1);
        const int hi = ((dt * 2 + (c >> 3)) & 3) << 4;
#pragma unroll
        for (int r = 0; r < 4; ++r) {
            const int ln = (q * 4 + r) | hi;
            ab[(((size_t)kt * 64 + it) * 64 + ln) * 8 + (c & 7)] = f2bf(acc[dt][r] * inv[r]);
        }
    }
}

// ============ K5: out projection — LDS-free, barrier-free frag GEMM =========
// grid (64 nt, 8 b), 4 waves; wave owns 64 o-rows (m-tiles w*4..w*4+3) x 16 s.
__global__ __launch_bounds__(256) void out_proj(const short* __restrict__ wp,
                                                const short* __restrict__ aop,
                                                const float* __restrict__ bias,
                                                float* __restrict__ out) {
    const int t = threadIdx.x, lane = t & 63, w = t >> 6;
    const int nt = blockIdx.x, b = blockIdx.y;
    const int c = lane & 15, q = lane >> 4;

    const short* bp = aop + ((size_t)b * 1024 + nt) * 512 + lane * 8;  // +kt*32768
    const short* ap = wp + (size_t)lane * 8;                           // +(mt*16+kt)*512

    float4v acc[4];
#pragma unroll
    for (int i = 0; i < 4; ++i) acc[i] = (float4v){0.f, 0.f, 0.f, 0.f};

#pragma unroll 4
    for (int kt = 0; kt < 16; ++kt) {
        short8 bf_ = *(const short8*)(bp + (size_t)kt * 32768);
#pragma unroll
        for (int i = 0; i < 4; ++i) {
            short8 af = *(const short8*)(ap + (size_t)((w * 4 + i) * 16 + kt) * 512);
            acc[i] = __builtin_amdgcn_mfma_f32_16x16x32_bf16(af, bf_, acc[i], 0, 0, 0);
        }
    }

    float* ob = out + (size_t)b * CIN * SEQ;
#pragma unroll
    for (int i = 0; i < 4; ++i)
#pragma unroll
        for (int r = 0; r < 4; ++r) {
            const int o = w * 64 + i * 16 + q * 4 + r;
            ob[(size_t)o * SEQ + nt * 16 + c] = acc[i][r] + bias[o];
        }
}

extern "C" void kernel_launch(void* const* d_in, const int* in_sizes, int n_in,
                              void* d_out, int out_size, void* d_ws, size_t ws_size,
                              hipStream_t stream) {
    const float* x = (const float*)d_in[0];
    const float* w_qkv = (const float*)d_in[1];
    const float* w_out = (const float*)d_in[2];
    const float* b_out = (const float*)d_in[3];
    float* out = (float*)d_out;

    char* wsp = (char*)d_ws;
    float* qkv = (float*)wsp;                        // 50.33 MB
    short* qp  = (short*)(wsp + 50331648);           // 8.39 MB
    short* kp  = (short*)(wsp + 58720256);           // 8.39 MB
    short* vp  = (short*)(wsp + 67108864);           // 8.39 MB
    short* aop = (short*)(wsp + 75497472);           // 8.39 MB
    short* wpk = (short*)(wsp + 83886080);           // 0.26 MB  (total 84.1 MB)

    gemm_mfma<128, 2, 4, 4><<<dim3(8, 12, 8), 256, 0, stream>>>(
        w_qkv, x, qkv, OQKV, CIN);
    rope_pack<<<dim3(8, 64, 3), 256, 0, stream>>>(qkv, qp, kp, vp);
    pack_w<<<dim3(64), 256, 0, stream>>>(w_out, wpk);
    attn_mfma<<<dim3(16, 64), 256, 0, stream>>>(qp, kp, vp, aop);
    out_proj<<<dim3(64, 8), 256, 0, stream>>>(wpk, aop, b_out, out);
}

// Round 7
// 186.250 us; speedup vs baseline: 1.3441x; 1.0808x over previous
//
#include <hip/hip_runtime.h>
#include <math.h>

#define NB 8
#define CIN 256
#define SEQ 1024
#define NH 8
#define DH 64
#define HID 512
#define OQKV 1536

typedef __attribute__((ext_vector_type(8))) short short8;
typedef __attribute__((ext_vector_type(4))) short short4v;
typedef __attribute__((ext_vector_type(4))) float float4v;

static __device__ inline short f2bf(float x) {  // RNE
    union { float f; unsigned u; } c; c.f = x;
    unsigned r = (c.u + 0x7FFFu + ((c.u >> 16) & 1u)) >> 16;
    return (short)r;
}
static __device__ inline float bf2f(short h) {
    union { unsigned u; float f; } c; c.u = ((unsigned)(unsigned short)h) << 16;
    return c.f;
}

#define LP 36

// ============ K1: fused qkv GEMM + RoPE + ssq + frag-pack ===================
// BM=64 (one head per wave-row; all 4 waves share rows, split n), BN=128,
// BK=32. grid (8 n, 24 m, 8 b). zone = m-block/8: 0=q,1=k,2=v.
// Epilogue: RoPE acc[0]<->acc[1] (d, d+16), atomicAdd row ssq, scatter
// bf16 into packed frag layouts (q/k: [slice,st,qp,c,e]; v: [jt,dt,qp,c,e]).
__global__ __launch_bounds__(256) void qkv_fused(const float* __restrict__ x,
                                                 const float* __restrict__ w,
                                                 short* __restrict__ qp,
                                                 short* __restrict__ kp,
                                                 short* __restrict__ vp,
                                                 float* __restrict__ ssq) {
    __shared__ __align__(16) short As[64 * LP];
    __shared__ __align__(16) short Bs[128 * LP];
    const int t = threadIdx.x, lane = t & 63, wv = t >> 6;
    const int c = lane & 15, q = lane >> 4;
    const int b = blockIdx.z;
    const int m0 = blockIdx.y * 64;
    const int n0 = blockIdx.x * 128;
    const int zone = blockIdx.y >> 3, h = blockIdx.y & 7;
    const int bh = b * 8 + h;

    const float* Ab = w + (size_t)m0 * CIN;
    const float* Bb = x + (size_t)b * CIN * SEQ + n0;

    float4v acc[4][2];
#pragma unroll
    for (int i = 0; i < 4; ++i)
#pragma unroll
        for (int j = 0; j < 2; ++j) acc[i][j] = (float4v){0.f, 0.f, 0.f, 0.f};

    for (int k0 = 0; k0 < CIN; k0 += 32) {
        __syncthreads();
#pragma unroll
        for (int qq = t; qq < 64 * 8; qq += 256) {
            int m = qq >> 3, kq = (qq & 7) * 4;
            float4v v = *(const float4v*)(Ab + (size_t)m * CIN + k0 + kq);
            short4v s4;
#pragma unroll
            for (int cc = 0; cc < 4; ++cc) s4[cc] = f2bf(v[cc]);
            *(short4v*)&As[m * LP + kq] = s4;
        }
#pragma unroll
        for (int qq = t; qq < 128 * 8; qq += 256) {
            int n = qq & 127, kq = (qq >> 7) * 4;
            short4v s4;
#pragma unroll
            for (int cc = 0; cc < 4; ++cc)
                s4[cc] = f2bf(Bb[(size_t)(k0 + kq + cc) * SEQ + n]);
            *(short4v*)&Bs[n * LP + kq] = s4;
        }
        __syncthreads();

        const int koff = q * 8;
        short8 af[4], bfr[2];
#pragma unroll
        for (int i = 0; i < 4; ++i) {
            int m = i * 16 + c;
            short4v lo = *(const short4v*)&As[m * LP + koff];
            short4v hi = *(const short4v*)&As[m * LP + koff + 4];
            af[i] = (short8){lo[0], lo[1], lo[2], lo[3], hi[0], hi[1], hi[2], hi[3]};
        }
#pragma unroll
        for (int j = 0; j < 2; ++j) {
            int n = wv * 32 + j * 16 + c;
            short4v lo = *(const short4v*)&Bs[n * LP + koff];
            short4v hi = *(const short4v*)&Bs[n * LP + koff + 4];
            bfr[j] = (short8){lo[0], lo[1], lo[2], lo[3], hi[0], hi[1], hi[2], hi[3]};
        }
#pragma unroll
        for (int i = 0; i < 4; ++i)
#pragma unroll
            for (int j = 0; j < 2; ++j)
                acc[i][j] = __builtin_amdgcn_mfma_f32_16x16x32_bf16(af[i], bfr[j],
                                                                    acc[i][j], 0, 0, 0);
    }

    const int sbase = n0 + wv * 32;
    if (zone < 2) {
        // ---- RoPE: rows d = q*4+r (acc[0]) pair with d+16 (acc[1]) ----
#pragma unroll
        for (int r = 0; r < 4; ++r) {
            const int d = q * 4 + r;
            const float invf = exp2f(-(float)d * 0.83048202372184045f);  // 10000^(-d/16)
#pragma unroll
            for (int j = 0; j < 2; ++j) {
                float ang = (float)(sbase + j * 16 + c) * invf;
                float sn, cs;
                __sincosf(ang, &sn, &cs);
                float v0 = acc[0][j][r], v1 = acc[1][j][r];
                acc[0][j][r] = v0 * cs - v1 * sn;
                acc[1][j][r] = v1 * cs + v0 * sn;
            }
        }
        // ---- per-row squared-sum partials -> atomicAdd ----
        float* sq = ssq + (size_t)b * 1024 + zone * 512 + h * 64;
#pragma unroll
        for (int i = 0; i < 4; ++i)
#pragma unroll
            for (int r = 0; r < 4; ++r) {
                float val = acc[i][0][r] * acc[i][0][r] + acc[i][1][r] * acc[i][1][r];
#pragma unroll
                for (int o = 1; o < 16; o <<= 1) val += __shfl_xor(val, o, 64);
                if (c == 0) atomicAdd(&sq[i * 16 + q * 4 + r], val);
            }
        // ---- scatter roped (unnormalized) bf16 into q/k frag layout ----
        short* dst = (zone ? kp : qp) + (size_t)bh * 65536;
#pragma unroll
        for (int i = 0; i < 4; ++i) {
            const int st = i >> 1;
#pragma unroll
            for (int r = 0; r < 4; ++r) {
                const int dq = q * 4 + r;
                const int qp_ = (2 * i + (dq >> 3)) & 3;
                const int e = dq & 7;
#pragma unroll
                for (int j = 0; j < 2; ++j) {
                    const int slice = (sbase >> 4) + j;
                    dst[(((size_t)slice * 2 + st) * 64 + qp_ * 16 + c) * 8 + e] =
                        f2bf(acc[i][j][r]);
                }
            }
        }
    } else {
        // ---- V: scatter into PV B-frag layout ----
        short* dst = vp + (size_t)bh * 65536;
        const int jt = sbase >> 5;
#pragma unroll
        for (int i = 0; i < 4; ++i)
#pragma unroll
            for (int j = 0; j < 2; ++j) {
                const int s_ = sbase + j * 16 + c;
                const int qpart = (s_ >> 3) & 3, e = s_ & 7;
#pragma unroll
                for (int r = 0; r < 4; ++r)
                    dst[(((size_t)jt * 4 + i) * 64 + qpart * 16 + (q * 4 + r)) * 8 + e] =
                        f2bf(acc[i][j][r]);
            }
    }
}

// ============ K2: normalize q in place: x 10/(nq[d]*nk[d]) ==================
// grid (32, 64 bh). Each thread rescales one short8 (8 consecutive d).
__global__ __launch_bounds__(256) void normalize_q(short* __restrict__ qp,
                                                   const float* __restrict__ ssq) {
    __shared__ float scale[64];
    const int t = threadIdx.x;
    const int bh = blockIdx.y, b = bh >> 3, h = bh & 7;
    if (t < 64) {
        float s1 = ssq[(size_t)b * 1024 + h * 64 + t];
        float s2 = ssq[(size_t)b * 1024 + 512 + h * 64 + t];
        scale[t] = 10.f / (fmaxf(sqrtf(s1), 1e-12f) * fmaxf(sqrtf(s2), 1e-12f));
    }
    __syncthreads();
    const int idx = blockIdx.x * 256 + t;
    short* p = qp + (size_t)bh * 65536 + (size_t)idx * 8;
    short8 v = *(const short8*)p;
    const int d0 = ((idx >> 6) & 1) * 32 + ((idx >> 4) & 3) * 8;
#pragma unroll
    for (int e = 0; e < 8; ++e) v[e] = f2bf(bf2f(v[e]) * scale[d0 + e]);
    *(short8*)p = v;
}

// ============ K3: pack w_out into A-frag order bf16 (tiny) ==================
__global__ __launch_bounds__(256) void pack_w(const float* __restrict__ w_out,
                                              short* __restrict__ wp) {
    const int t = threadIdx.x, lane = t & 63, wv = t >> 6;
    const int fid = blockIdx.x * 4 + wv;  // 0..255: mt = fid>>4, kt = fid&15
    const int m = (fid >> 4) * 16 + (lane & 15);
    const int k0 = (fid & 15) * 32 + (lane >> 4) * 8;
    const float* p = w_out + (size_t)m * HID + k0;
    float4v lo = *(const float4v*)p;
    float4v hi = *(const float4v*)(p + 4);
    short8 v;
#pragma unroll
    for (int e = 0; e < 4; ++e) { v[e] = f2bf(lo[e]); v[4 + e] = f2bf(hi[e]); }
    *(short8*)(wp + (size_t)fid * 512 + lane * 8) = v;
}

// ============ K4: attention (barrier-free), bf16 B-frag output ==============
__global__ __launch_bounds__(256) void attn_mfma(const short* __restrict__ qp,
                                                 const short* __restrict__ kp,
                                                 const short* __restrict__ vp,
                                                 short* __restrict__ aop) {
    __shared__ __align__(16) short pt[4][16][40];  // per-wave P tile, 80B pitch
    const int t = threadIdx.x, lane = t & 63, wv = t >> 6;
    const int bh = blockIdx.y, b = bh >> 3, h = bh & 7;
    const int it = blockIdx.x * 4 + wv;  // 0..63
    const int c = lane & 15, q = lane >> 4;

    const short* qpb = qp + (((size_t)bh * 64 + it) * 2 * 64 + lane) * 8;
    short8 aq0 = *(const short8*)qpb;
    short8 aq1 = *(const short8*)(qpb + 512);

    short8 ones;
#pragma unroll
    for (int e = 0; e < 8; ++e) ones[e] = (short)0x3F80;  // bf16(1.0)

    float4v acc[4];
#pragma unroll
    for (int dt = 0; dt < 4; ++dt) acc[dt] = (float4v){0.f, 0.f, 0.f, 0.f};
    float4v accS = (float4v){0.f, 0.f, 0.f, 0.f};

    for (int jt = 0; jt < 32; ++jt) {
        const short* kbb = kp + (((size_t)bh * 64 + jt * 2) * 2 * 64 + lane) * 8;
        short8 bk00 = *(const short8*)kbb;
        short8 bk01 = *(const short8*)(kbb + 512);
        short8 bk10 = *(const short8*)(kbb + 1024);
        short8 bk11 = *(const short8*)(kbb + 1536);
        const short* vbb = vp + (((size_t)bh * 32 + jt) * 4 * 64 + lane) * 8;
        short8 bv0 = *(const short8*)vbb;
        short8 bv1 = *(const short8*)(vbb + 512);
        short8 bv2 = *(const short8*)(vbb + 1024);
        short8 bv3 = *(const short8*)(vbb + 1536);

        // S^T = K.Q'^T (Q' has 10/(nq*nk) folded): C col axis = i
        float4v s0 = (float4v){0.f, 0.f, 0.f, 0.f};
        float4v s1 = (float4v){0.f, 0.f, 0.f, 0.f};
        s0 = __builtin_amdgcn_mfma_f32_16x16x32_bf16(bk00, aq0, s0, 0, 0, 0);
        s0 = __builtin_amdgcn_mfma_f32_16x16x32_bf16(bk01, aq1, s0, 0, 0, 0);
        s1 = __builtin_amdgcn_mfma_f32_16x16x32_bf16(bk10, aq0, s1, 0, 0, 0);
        s1 = __builtin_amdgcn_mfma_f32_16x16x32_bf16(bk11, aq1, s1, 0, 0, 0);

        // P^T = exp(S^T) -> truncate to bf16 pairs -> per-wave LDS tile
        int* ptw = (int*)&pt[wv][c][0];
#pragma unroll
        for (int jh = 0; jh < 2; ++jh) {
            float4v s = jh ? s1 : s0;
            unsigned u0 = __float_as_uint(__expf(s[0]));
            unsigned u1 = __float_as_uint(__expf(s[1]));
            unsigned u2 = __float_as_uint(__expf(s[2]));
            unsigned u3 = __float_as_uint(__expf(s[3]));
            ptw[jh * 8 + q * 2]     = (int)((u1 & 0xFFFF0000u) | (u0 >> 16));
            ptw[jh * 8 + q * 2 + 1] = (int)((u3 & 0xFFFF0000u) | (u2 >> 16));
        }
        short8 ap = *(const short8*)&pt[wv][c][q * 8];  // A-frag: m=i, k=j

        acc[0] = __builtin_amdgcn_mfma_f32_16x16x32_bf16(ap, bv0, acc[0], 0, 0, 0);
        acc[1] = __builtin_amdgcn_mfma_f32_16x16x32_bf16(ap, bv1, acc[1], 0, 0, 0);
        acc[2] = __builtin_amdgcn_mfma_f32_16x16x32_bf16(ap, bv2, acc[2], 0, 0, 0);
        acc[3] = __builtin_amdgcn_mfma_f32_16x16x32_bf16(ap, bv3, acc[3], 0, 0, 0);
        accS   = __builtin_amdgcn_mfma_f32_16x16x32_bf16(ap, ones, accS, 0, 0, 0);
    }

    float inv[4];
#pragma unroll
    for (int r = 0; r < 4; ++r) inv[r] = 1.0f / accS[r];

    // scatter bf16 output directly into out_proj B-frag order
    short* ab = aop + (size_t)b * 524288;
#pragma unroll
    for (int dt = 0; dt < 4; ++dt) {
        const int kt = h * 2 + (dt >> 1);
        const int hi = ((dt * 2 + (c >> 3)) & 3) << 4;
#pragma unroll
        for (int r = 0; r < 4; ++r) {
            const int ln = (q * 4 + r) | hi;
            ab[(((size_t)kt * 64 + it) * 64 + ln) * 8 + (c & 7)] = f2bf(acc[dt][r] * inv[r]);
        }
    }
}

// ============ K5: out projection — LDS-free, barrier-free frag GEMM =========
__global__ __launch_bounds__(256) void out_proj(const short* __restrict__ wp,
                                                const short* __restrict__ aop,
                                                const float* __restrict__ bias,
                                                float* __restrict__ out) {
    const int t = threadIdx.x, lane = t & 63, w = t >> 6;
    const int nt = blockIdx.x, b = blockIdx.y;
    const int c = lane & 15, q = lane >> 4;

    const short* bp = aop + ((size_t)b * 1024 + nt) * 512 + lane * 8;
    const short* ap = wp + (size_t)lane * 8;

    float4v acc[4];
#pragma unroll
    for (int i = 0; i < 4; ++i) acc[i] = (float4v){0.f, 0.f, 0.f, 0.f};

#pragma unroll 4
    for (int kt = 0; kt < 16; ++kt) {
        short8 bf_ = *(const short8*)(bp + (size_t)kt * 32768);
#pragma unroll
        for (int i = 0; i < 4; ++i) {
            short8 af = *(const short8*)(ap + (size_t)((w * 4 + i) * 16 + kt) * 512);
            acc[i] = __builtin_amdgcn_mfma_f32_16x16x32_bf16(af, bf_, acc[i], 0, 0, 0);
        }
    }

    float* ob = out + (size_t)b * CIN * SEQ;
#pragma unroll
    for (int i = 0; i < 4; ++i)
#pragma unroll
        for (int r = 0; r < 4; ++r) {
            const int o = w * 64 + i * 16 + q * 4 + r;
            ob[(size_t)o * SEQ + nt * 16 + c] = acc[i][r] + bias[o];
        }
}

extern "C" void kernel_launch(void* const* d_in, const int* in_sizes, int n_in,
                              void* d_out, int out_size, void* d_ws, size_t ws_size,
                              hipStream_t stream) {
    const float* x = (const float*)d_in[0];
    const float* w_qkv = (const float*)d_in[1];
    const float* w_out = (const float*)d_in[2];
    const float* b_out = (const float*)d_in[3];
    float* out = (float*)d_out;

    char* wsp = (char*)d_ws;
    short* qp  = (short*)wsp;                        // 8.39 MB
    short* kp  = (short*)(wsp + 8388608);            // 8.39 MB
    short* vp  = (short*)(wsp + 16777216);           // 8.39 MB
    short* aop = (short*)(wsp + 25165824);           // 8.39 MB
    short* wpk = (short*)(wsp + 33554432);           // 0.26 MB
    float* ssq = (float*)(wsp + 33816576);           // 32 KB   (total ~33.9 MB)

    hipMemsetAsync(ssq, 0, NB * 1024 * sizeof(float), stream);
    qkv_fused<<<dim3(8, 24, 8), 256, 0, stream>>>(x, w_qkv, qp, kp, vp, ssq);
    normalize_q<<<dim3(32, 64), 256, 0, stream>>>(qp, ssq);
    pack_w<<<dim3(64), 256, 0, stream>>>(w_out, wpk);
    attn_mfma<<<dim3(16, 64), 256, 0, stream>>>(qp, kp, vp, aop);
    out_proj<<<dim3(64, 8), 256, 0, stream>>>(wpk, aop, b_out, out);
}

// Round 8
// 149.259 us; speedup vs baseline: 1.6773x; 1.2478x over previous
//
#include <hip/hip_runtime.h>
#include <math.h>

#define NB 8
#define CIN 256
#define SEQ 1024
#define NH 8
#define DH 64
#define HID 512
#define OQKV 1536

typedef __attribute__((ext_vector_type(8))) short short8;
typedef __attribute__((ext_vector_type(4))) short short4v;
typedef __attribute__((ext_vector_type(4))) float float4v;

static __device__ inline short f2bf(float x) {  // RNE
    union { float f; unsigned u; } c; c.f = x;
    unsigned r = (c.u + 0x7FFFu + ((c.u >> 16) & 1u)) >> 16;
    return (short)r;
}
static __device__ inline float bf2f(short h) {
    union { unsigned u; float f; } c; c.u = ((unsigned)(unsigned short)h) << 16;
    return c.f;
}

// ============ K0a: pack x into B-frag order bf16 ===========================
// frag (b,kt,nt): B[k=kt*32+q*8+e][n=nt*16+c] -> xp[fid*512 + lane*8 + e],
// fid = b*512 + kt*64 + nt.
__global__ __launch_bounds__(256) void pack_x(const float* __restrict__ x,
                                              short* __restrict__ xp) {
    const int t = threadIdx.x, lane = t & 63, wv = t >> 6;
    const int fid = blockIdx.x * 4 + wv;  // 0..4095
    const int b = fid >> 9, kt = (fid >> 6) & 7, nt = fid & 63;
    const int c = lane & 15, q = lane >> 4;
    const float* src = x + ((size_t)(b * 256 + kt * 32 + q * 8)) * SEQ + nt * 16 + c;
    short8 v;
#pragma unroll
    for (int e = 0; e < 8; ++e) v[e] = f2bf(src[(size_t)e * SEQ]);
    *(short8*)(xp + (size_t)fid * 512 + lane * 8) = v;
}

// ============ K0b: pack w_qkv into A-frag order bf16 =======================
// frag (mt,kt): A[m=mt*16+c][k=kt*32+q*8+e] -> wqp[(mt*8+kt)*512 + lane*8+e]
__global__ __launch_bounds__(256) void pack_wq(const float* __restrict__ w,
                                               short* __restrict__ wqp) {
    const int t = threadIdx.x, lane = t & 63, wv = t >> 6;
    const int fid = blockIdx.x * 4 + wv;  // 0..767
    const int m = (fid >> 3) * 16 + (lane & 15);
    const int k0 = (fid & 7) * 32 + (lane >> 4) * 8;
    const float* p = w + (size_t)m * CIN + k0;
    float4v lo = *(const float4v*)p;
    float4v hi = *(const float4v*)(p + 4);
    short8 v;
#pragma unroll
    for (int e = 0; e < 4; ++e) { v[e] = f2bf(lo[e]); v[4 + e] = f2bf(hi[e]); }
    *(short8*)(wqp + (size_t)fid * 512 + lane * 8) = v;
}

// ============ K0c: pack w_out into A-frag order bf16 =======================
__global__ __launch_bounds__(256) void pack_w(const float* __restrict__ w_out,
                                              short* __restrict__ wp) {
    const int t = threadIdx.x, lane = t & 63, wv = t >> 6;
    const int fid = blockIdx.x * 4 + wv;  // 0..255: mt=fid>>4, kt=fid&15
    const int m = (fid >> 4) * 16 + (lane & 15);
    const int k0 = (fid & 15) * 32 + (lane >> 4) * 8;
    const float* p = w_out + (size_t)m * HID + k0;
    float4v lo = *(const float4v*)p;
    float4v hi = *(const float4v*)(p + 4);
    short8 v;
#pragma unroll
    for (int e = 0; e < 4; ++e) { v[e] = f2bf(lo[e]); v[4 + e] = f2bf(hi[e]); }
    *(short8*)(wp + (size_t)fid * 512 + lane * 8) = v;
}

// ============ K1: qkv projection — LDS-free barrier-free frag GEMM =========
// grid (16 ntp, 6, 8 b); wave zh = by*4+wv (zone*8+h), owns 64 m x 64 s.
// Epilogue (fused, verified R7): RoPE acc[0]<->acc[1], ssq atomics, scatter
// bf16 into q/k A-frag layout and V B-frag layout.
__global__ __launch_bounds__(256) void qkv_frag(const short* __restrict__ xp,
                                                const short* __restrict__ wqp,
                                                short* __restrict__ qp,
                                                short* __restrict__ kp,
                                                short* __restrict__ vp,
                                                float* __restrict__ ssq) {
    const int t = threadIdx.x, lane = t & 63, wv = t >> 6;
    const int c = lane & 15, q = lane >> 4;
    const int b = blockIdx.z;
    const int zh = blockIdx.y * 4 + wv;  // 0..23
    const int zone = zh >> 3, h = zh & 7;
    const int bh = b * 8 + h;
    const int nt0 = blockIdx.x * 4;      // 4 n-tiles = 64 s

    const short* bp = xp + ((size_t)b * 512 + nt0) * 512 + lane * 8;
    const short* ap = wqp + (size_t)zh * 32 * 512 + lane * 8;

    float4v acc[4][4];
#pragma unroll
    for (int i = 0; i < 4; ++i)
#pragma unroll
        for (int j = 0; j < 4; ++j) acc[i][j] = (float4v){0.f, 0.f, 0.f, 0.f};

#pragma unroll 2
    for (int kt = 0; kt < 8; ++kt) {
        short8 bfr[4], af[4];
#pragma unroll
        for (int j = 0; j < 4; ++j)
            bfr[j] = *(const short8*)(bp + ((size_t)kt * 64 + j) * 512);
#pragma unroll
        for (int i = 0; i < 4; ++i)
            af[i] = *(const short8*)(ap + (size_t)(i * 8 + kt) * 512);
#pragma unroll
        for (int i = 0; i < 4; ++i)
#pragma unroll
            for (int j = 0; j < 4; ++j)
                acc[i][j] = __builtin_amdgcn_mfma_f32_16x16x32_bf16(af[i], bfr[j],
                                                                    acc[i][j], 0, 0, 0);
    }

    if (zone < 2) {
        // ---- RoPE: acc[0] rows d=q*4+r pair with acc[1] rows d+16 ----
#pragma unroll
        for (int r = 0; r < 4; ++r) {
            const int d = q * 4 + r;
            const float invf = exp2f(-(float)d * 0.83048202372184045f);  // 10000^(-d/16)
#pragma unroll
            for (int j = 0; j < 4; ++j) {
                float ang = (float)((nt0 + j) * 16 + c) * invf;
                float sn, cs;
                __sincosf(ang, &sn, &cs);
                float v0 = acc[0][j][r], v1 = acc[1][j][r];
                acc[0][j][r] = v0 * cs - v1 * sn;
                acc[1][j][r] = v1 * cs + v0 * sn;
            }
        }
        // ---- per-row ssq partials ----
        float* sq = ssq + (size_t)b * 1024 + zone * 512 + h * 64;
#pragma unroll
        for (int i = 0; i < 4; ++i)
#pragma unroll
            for (int r = 0; r < 4; ++r) {
                float val = 0.f;
#pragma unroll
                for (int j = 0; j < 4; ++j) val += acc[i][j][r] * acc[i][j][r];
#pragma unroll
                for (int o = 1; o < 16; o <<= 1) val += __shfl_xor(val, o, 64);
                if (c == 0) atomicAdd(&sq[i * 16 + q * 4 + r], val);
            }
        // ---- scatter roped (unnormalized) bf16 into q/k frag layout ----
        short* dst = (zone ? kp : qp) + (size_t)bh * 65536;
#pragma unroll
        for (int i = 0; i < 4; ++i) {
            const int st = i >> 1;
#pragma unroll
            for (int r = 0; r < 4; ++r) {
                const int dq = q * 4 + r;
                const int qp_ = (2 * i + (dq >> 3)) & 3;
                const int e = dq & 7;
#pragma unroll
                for (int j = 0; j < 4; ++j) {
                    const int slice = nt0 + j;
                    dst[(((size_t)slice * 2 + st) * 64 + qp_ * 16 + c) * 8 + e] =
                        f2bf(acc[i][j][r]);
                }
            }
        }
    } else {
        // ---- V: scatter into PV B-frag layout ----
        short* dst = vp + (size_t)bh * 65536;
#pragma unroll
        for (int j = 0; j < 4; ++j) {
            const int s_ = (nt0 + j) * 16 + c;
            const int jt = s_ >> 5, qpart = (s_ >> 3) & 3, e = s_ & 7;
#pragma unroll
            for (int i = 0; i < 4; ++i)
#pragma unroll
                for (int r = 0; r < 4; ++r)
                    dst[(((size_t)jt * 4 + i) * 64 + qpart * 16 + (q * 4 + r)) * 8 + e] =
                        f2bf(acc[i][j][r]);
        }
    }
}

// ============ K2: normalize q in place: x 10/(nq[d]*nk[d]) ==================
__global__ __launch_bounds__(256) void normalize_q(short* __restrict__ qp,
                                                   const float* __restrict__ ssq) {
    __shared__ float scale[64];
    const int t = threadIdx.x;
    const int bh = blockIdx.y, b = bh >> 3, h = bh & 7;
    if (t < 64) {
        float s1 = ssq[(size_t)b * 1024 + h * 64 + t];
        float s2 = ssq[(size_t)b * 1024 + 512 + h * 64 + t];
        scale[t] = 10.f / (fmaxf(sqrtf(s1), 1e-12f) * fmaxf(sqrtf(s2), 1e-12f));
    }
    __syncthreads();
    const int idx = blockIdx.x * 256 + t;
    short* p = qp + (size_t)bh * 65536 + (size_t)idx * 8;
    short8 v = *(const short8*)p;
    const int d0 = ((idx >> 6) & 1) * 32 + ((idx >> 4) & 3) * 8;
#pragma unroll
    for (int e = 0; e < 8; ++e) v[e] = f2bf(bf2f(v[e]) * scale[d0 + e]);
    *(short8*)p = v;
}

// ============ K3: attention, barrier-free, 2 i-tiles per wave ==============
__global__ __launch_bounds__(256) void attn_mfma(const short* __restrict__ qp,
                                                 const short* __restrict__ kp,
                                                 const short* __restrict__ vp,
                                                 short* __restrict__ aop) {
    __shared__ __align__(16) short pt[4][16][40];  // per-wave P tile, 80B pitch
    const int t = threadIdx.x, lane = t & 63, wv = t >> 6;
    const int bh = blockIdx.y, b = bh >> 3, h = bh & 7;
    const int it0 = (blockIdx.x * 4 + wv) * 2;  // 2 i-tiles per wave
    const int c = lane & 15, q = lane >> 4;

    short8 aq[2][2];
#pragma unroll
    for (int u = 0; u < 2; ++u) {
        const short* qpb = qp + (size_t)bh * 65536 + (size_t)(it0 + u) * 1024 + lane * 8;
        aq[u][0] = *(const short8*)qpb;
        aq[u][1] = *(const short8*)(qpb + 512);
    }

    short8 ones;
#pragma unroll
    for (int e = 0; e < 8; ++e) ones[e] = (short)0x3F80;  // bf16(1.0)

    float4v acc[2][4], accS[2];
#pragma unroll
    for (int u = 0; u < 2; ++u) {
        accS[u] = (float4v){0.f, 0.f, 0.f, 0.f};
#pragma unroll
        for (int dt = 0; dt < 4; ++dt) acc[u][dt] = (float4v){0.f, 0.f, 0.f, 0.f};
    }

    for (int jt = 0; jt < 32; ++jt) {
        const short* kbb = kp + (size_t)bh * 65536 + (size_t)jt * 2048 + lane * 8;
        short8 bk00 = *(const short8*)kbb;
        short8 bk01 = *(const short8*)(kbb + 512);
        short8 bk10 = *(const short8*)(kbb + 1024);
        short8 bk11 = *(const short8*)(kbb + 1536);
        const short* vbb = vp + (size_t)bh * 65536 + (size_t)jt * 2048 + lane * 8;
        short8 bv0 = *(const short8*)vbb;
        short8 bv1 = *(const short8*)(vbb + 512);
        short8 bv2 = *(const short8*)(vbb + 1024);
        short8 bv3 = *(const short8*)(vbb + 1536);

#pragma unroll
        for (int u = 0; u < 2; ++u) {
            // S^T = K.Q'^T (Q' has 10/(nq*nk) folded): C col axis = i
            float4v s0 = (float4v){0.f, 0.f, 0.f, 0.f};
            float4v s1 = (float4v){0.f, 0.f, 0.f, 0.f};
            s0 = __builtin_amdgcn_mfma_f32_16x16x32_bf16(bk00, aq[u][0], s0, 0, 0, 0);
            s0 = __builtin_amdgcn_mfma_f32_16x16x32_bf16(bk01, aq[u][1], s0, 0, 0, 0);
            s1 = __builtin_amdgcn_mfma_f32_16x16x32_bf16(bk10, aq[u][0], s1, 0, 0, 0);
            s1 = __builtin_amdgcn_mfma_f32_16x16x32_bf16(bk11, aq[u][1], s1, 0, 0, 0);

            // P^T = exp(S^T) -> truncate bf16 pairs -> per-wave LDS tile
            int* ptw = (int*)&pt[wv][c][0];
#pragma unroll
            for (int jh = 0; jh < 2; ++jh) {
                float4v s = jh ? s1 : s0;
                unsigned u0 = __float_as_uint(__expf(s[0]));
                unsigned u1 = __float_as_uint(__expf(s[1]));
                unsigned u2 = __float_as_uint(__expf(s[2]));
                unsigned u3 = __float_as_uint(__expf(s[3]));
                ptw[jh * 8 + q * 2]     = (int)((u1 & 0xFFFF0000u) | (u0 >> 16));
                ptw[jh * 8 + q * 2 + 1] = (int)((u3 & 0xFFFF0000u) | (u2 >> 16));
            }
            short8 ap = *(const short8*)&pt[wv][c][q * 8];  // A-frag: m=i, k=j

            acc[u][0] = __builtin_amdgcn_mfma_f32_16x16x32_bf16(ap, bv0, acc[u][0], 0, 0, 0);
            acc[u][1] = __builtin_amdgcn_mfma_f32_16x16x32_bf16(ap, bv1, acc[u][1], 0, 0, 0);
            acc[u][2] = __builtin_amdgcn_mfma_f32_16x16x32_bf16(ap, bv2, acc[u][2], 0, 0, 0);
            acc[u][3] = __builtin_amdgcn_mfma_f32_16x16x32_bf16(ap, bv3, acc[u][3], 0, 0, 0);
            accS[u]   = __builtin_amdgcn_mfma_f32_16x16x32_bf16(ap, ones, accS[u], 0, 0, 0);
        }
    }

    // scatter bf16 output directly into out_proj B-frag order
    short* ab = aop + (size_t)b * 524288;
#pragma unroll
    for (int u = 0; u < 2; ++u) {
        const int it = it0 + u;
        float inv[4];
#pragma unroll
        for (int r = 0; r < 4; ++r) inv[r] = 1.0f / accS[u][r];
#pragma unroll
        for (int dt = 0; dt < 4; ++dt) {
            const int kt = h * 2 + (dt >> 1);
            const int hi = ((dt * 2 + (c >> 3)) & 3) << 4;
#pragma unroll
            for (int r = 0; r < 4; ++r) {
                const int ln = (q * 4 + r) | hi;
                ab[(((size_t)kt * 64 + it) * 64 + ln) * 8 + (c & 7)] =
                    f2bf(acc[u][dt][r] * inv[r]);
            }
        }
    }
}

// ============ K4: out projection — LDS-free, barrier-free frag GEMM =========
__global__ __launch_bounds__(256) void out_proj(const short* __restrict__ wp,
                                                const short* __restrict__ aop,
                                                const float* __restrict__ bias,
                                                float* __restrict__ out) {
    const int t = threadIdx.x, lane = t & 63, w = t >> 6;
    const int nt = blockIdx.x, b = blockIdx.y;
    const int c = lane & 15, q = lane >> 4;

    const short* bp = aop + ((size_t)b * 1024 + nt) * 512 + lane * 8;
    const short* ap = wp + (size_t)lane * 8;

    float4v acc[4];
#pragma unroll
    for (int i = 0; i < 4; ++i) acc[i] = (float4v){0.f, 0.f, 0.f, 0.f};

#pragma unroll 4
    for (int kt = 0; kt < 16; ++kt) {
        short8 bf_ = *(const short8*)(bp + (size_t)kt * 32768);
#pragma unroll
        for (int i = 0; i < 4; ++i) {
            short8 af = *(const short8*)(ap + (size_t)((w * 4 + i) * 16 + kt) * 512);
            acc[i] = __builtin_amdgcn_mfma_f32_16x16x32_bf16(af, bf_, acc[i], 0, 0, 0);
        }
    }

    float* ob = out + (size_t)b * CIN * SEQ;
#pragma unroll
    for (int i = 0; i < 4; ++i)
#pragma unroll
        for (int r = 0; r < 4; ++r) {
            const int o = w * 64 + i * 16 + q * 4 + r;
            ob[(size_t)o * SEQ + nt * 16 + c] = acc[i][r] + bias[o];
        }
}

extern "C" void kernel_launch(void* const* d_in, const int* in_sizes, int n_in,
                              void* d_out, int out_size, void* d_ws, size_t ws_size,
                              hipStream_t stream) {
    const float* x = (const float*)d_in[0];
    const float* w_qkv = (const float*)d_in[1];
    const float* w_out = (const float*)d_in[2];
    const float* b_out = (const float*)d_in[3];
    float* out = (float*)d_out;

    char* wsp = (char*)d_ws;
    short* qp  = (short*)wsp;                        // 8.39 MB
    short* kp  = (short*)(wsp + 8388608);            // 8.39 MB
    short* vp  = (short*)(wsp + 16777216);           // 8.39 MB
    short* aop = (short*)(wsp + 25165824);           // 8.39 MB
    short* wpk = (short*)(wsp + 33554432);           // 0.26 MB
    float* ssq = (float*)(wsp + 33816576);           // 32 KB
    short* xp  = (short*)(wsp + 33849344);           // 4.19 MB
    short* wqp = (short*)(wsp + 38043648);           // 0.79 MB (total 38.8 MB)

    hipMemsetAsync(ssq, 0, NB * 1024 * sizeof(float), stream);
    pack_x<<<dim3(1024), 256, 0, stream>>>(x, xp);
    pack_wq<<<dim3(192), 256, 0, stream>>>(w_qkv, wqp);
    pack_w<<<dim3(64), 256, 0, stream>>>(w_out, wpk);
    qkv_frag<<<dim3(16, 6, 8), 256, 0, stream>>>(xp, wqp, qp, kp, vp, ssq);
    normalize_q<<<dim3(32, 64), 256, 0, stream>>>(qp, ssq);
    attn_mfma<<<dim3(8, 64), 256, 0, stream>>>(qp, kp, vp, aop);
    out_proj<<<dim3(64, 8), 256, 0, stream>>>(wpk, aop, b_out, out);
}

// Round 9
// 138.482 us; speedup vs baseline: 1.8078x; 1.0778x over previous
//
#include <hip/hip_runtime.h>
#include <math.h>

#define NB 8
#define CIN 256
#define SEQ 1024
#define NH 8
#define DH 64
#define HID 512
#define OQKV 1536

typedef __attribute__((ext_vector_type(8))) short short8;
typedef __attribute__((ext_vector_type(4))) short short4v;
typedef __attribute__((ext_vector_type(4))) float float4v;

static __device__ inline short f2bf(float x) {  // RNE
    union { float f; unsigned u; } c; c.f = x;
    unsigned r = (c.u + 0x7FFFu + ((c.u >> 16) & 1u)) >> 16;
    return (short)r;
}
static __device__ inline float bf2f(short h) {
    union { unsigned u; float f; } c; c.u = ((unsigned)(unsigned short)h) << 16;
    return c.f;
}

// ============ K0: all input packs + ssq zero, one launch ====================
// blocks 0..1023: x -> B-frag bf16; 1024..1215: w_qkv -> A-frag;
// 1216..1279: w_out -> A-frag; 1280: zero ssq (8192 floats).
__global__ __launch_bounds__(256) void pack_all(const float* __restrict__ x,
                                                const float* __restrict__ w_qkv,
                                                const float* __restrict__ w_out,
                                                short* __restrict__ xp,
                                                short* __restrict__ wqp,
                                                short* __restrict__ wpk,
                                                float* __restrict__ ssq) {
    const int t = threadIdx.x, lane = t & 63, wv = t >> 6;
    const int bx = blockIdx.x;
    const int c = lane & 15, q = lane >> 4;
    if (bx < 1024) {
        const int fid = bx * 4 + wv;  // 0..4095
        const int b = fid >> 9, kt = (fid >> 6) & 7, nt = fid & 63;
        const float* src = x + ((size_t)(b * 256 + kt * 32 + q * 8)) * SEQ + nt * 16 + c;
        short8 v;
#pragma unroll
        for (int e = 0; e < 8; ++e) v[e] = f2bf(src[(size_t)e * SEQ]);
        *(short8*)(xp + (size_t)fid * 512 + lane * 8) = v;
    } else if (bx < 1216) {
        const int fid = (bx - 1024) * 4 + wv;  // 0..767
        const int m = (fid >> 3) * 16 + c;
        const int k0 = (fid & 7) * 32 + q * 8;
        const float* p = w_qkv + (size_t)m * CIN + k0;
        float4v lo = *(const float4v*)p;
        float4v hi = *(const float4v*)(p + 4);
        short8 v;
#pragma unroll
        for (int e = 0; e < 4; ++e) { v[e] = f2bf(lo[e]); v[4 + e] = f2bf(hi[e]); }
        *(short8*)(wqp + (size_t)fid * 512 + lane * 8) = v;
    } else if (bx < 1280) {
        const int fid = (bx - 1216) * 4 + wv;  // 0..255
        const int m = (fid >> 4) * 16 + c;
        const int k0 = (fid & 15) * 32 + q * 8;
        const float* p = w_out + (size_t)m * HID + k0;
        float4v lo = *(const float4v*)p;
        float4v hi = *(const float4v*)(p + 4);
        short8 v;
#pragma unroll
        for (int e = 0; e < 4; ++e) { v[e] = f2bf(lo[e]); v[4 + e] = f2bf(hi[e]); }
        *(short8*)(wpk + (size_t)fid * 512 + lane * 8) = v;
    } else {
        float4v z = (float4v){0.f, 0.f, 0.f, 0.f};
#pragma unroll
        for (int k = 0; k < 8; ++k) *((float4v*)ssq + t * 8 + k) = z;
    }
}

// ============ K1: qkv projection — LDS-free barrier-free frag GEMM =========
// grid (16 ntp, 6, 8 b); wave zh = by*4+wv = zone*8+h, owns 64 m x 64 s.
// zones 0/1 (q/k): C = W.X (m=d rows); zone 2 (v): transposed mfma -> m=s rows
// so register r runs along the e-axis of the vp frag layout (short4 stores).
__global__ __launch_bounds__(256) void qkv_frag(const short* __restrict__ xp,
                                                const short* __restrict__ wqp,
                                                short* __restrict__ qp,
                                                short* __restrict__ kp,
                                                short* __restrict__ vp,
                                                float* __restrict__ ssq) {
    const int t = threadIdx.x, lane = t & 63, wv = t >> 6;
    const int c = lane & 15, q = lane >> 4;
    const int b = blockIdx.z;
    const int zh = blockIdx.y * 4 + wv;  // 0..23
    const int zone = zh >> 3, h = zh & 7;
    const int bh = b * 8 + h;
    const int nt0 = blockIdx.x * 4;      // 4 n-tiles = 64 s

    const short* bp = xp + ((size_t)b * 512 + nt0) * 512 + lane * 8;
    const short* ap = wqp + (size_t)zh * 32 * 512 + lane * 8;

    float4v acc[4][4];
#pragma unroll
    for (int i = 0; i < 4; ++i)
#pragma unroll
        for (int j = 0; j < 4; ++j) acc[i][j] = (float4v){0.f, 0.f, 0.f, 0.f};

#pragma unroll 2
    for (int kt = 0; kt < 8; ++kt) {
        short8 bfr[4], af[4];
#pragma unroll
        for (int j = 0; j < 4; ++j)
            bfr[j] = *(const short8*)(bp + ((size_t)kt * 64 + j) * 512);
#pragma unroll
        for (int i = 0; i < 4; ++i)
            af[i] = *(const short8*)(ap + (size_t)(i * 8 + kt) * 512);
        if (zone < 2) {
#pragma unroll
            for (int i = 0; i < 4; ++i)
#pragma unroll
                for (int j = 0; j < 4; ++j)
                    acc[i][j] = __builtin_amdgcn_mfma_f32_16x16x32_bf16(af[i], bfr[j],
                                                                        acc[i][j], 0, 0, 0);
        } else {
#pragma unroll
            for (int i = 0; i < 4; ++i)
#pragma unroll
                for (int j = 0; j < 4; ++j)
                    acc[i][j] = __builtin_amdgcn_mfma_f32_16x16x32_bf16(bfr[j], af[i],
                                                                        acc[i][j], 0, 0, 0);
        }
    }

    if (zone < 2) {
        // ---- RoPE: acc[0] rows d=q*4+r pair with acc[1] rows d+16 ----
#pragma unroll
        for (int r = 0; r < 4; ++r) {
            const int d = q * 4 + r;
            const float invf = exp2f(-(float)d * 0.83048202372184045f);  // 10000^(-d/16)
#pragma unroll
            for (int j = 0; j < 4; ++j) {
                float ang = (float)((nt0 + j) * 16 + c) * invf;
                float sn, cs;
                __sincosf(ang, &sn, &cs);
                float v0 = acc[0][j][r], v1 = acc[1][j][r];
                acc[0][j][r] = v0 * cs - v1 * sn;
                acc[1][j][r] = v1 * cs + v0 * sn;
            }
        }
        // ---- per-row ssq partials -> atomicAdd ----
        float* sq = ssq + (size_t)b * 1024 + zone * 512 + h * 64;
#pragma unroll
        for (int i = 0; i < 4; ++i)
#pragma unroll
            for (int r = 0; r < 4; ++r) {
                float val = 0.f;
#pragma unroll
                for (int j = 0; j < 4; ++j) val += acc[i][j][r] * acc[i][j][r];
#pragma unroll
                for (int o = 1; o < 16; o <<= 1) val += __shfl_xor(val, o, 64);
                if (c == 0) atomicAdd(&sq[i * 16 + q * 4 + r], val);
            }
        // ---- scatter roped (unnormalized) bf16, contiguous short4 ----
        // d = i*16 + q*4 + r: st=i>>1, qp_=(2i+(q>>1))&3, e = (q&1)*4 + r
        short* dst = (zone ? kp : qp) + (size_t)bh * 65536;
        const int e0 = (q & 1) * 4;
#pragma unroll
        for (int i = 0; i < 4; ++i) {
            const int st = i >> 1;
            const int qp_ = (2 * i + (q >> 1)) & 3;
#pragma unroll
            for (int j = 0; j < 4; ++j) {
                const int slice = nt0 + j;
                short4v s4;
#pragma unroll
                for (int r = 0; r < 4; ++r) s4[r] = f2bf(acc[i][j][r]);
                *(short4v*)(dst + (((size_t)slice * 2 + st) * 64 + qp_ * 16 + c) * 8 + e0) = s4;
            }
        }
    } else {
        // ---- V (transposed tiles): s = (nt0+j)*16 + q*4 + r, d = i*16 + c ----
        short* dst = vp + (size_t)bh * 65536;
        const int e0 = (q & 1) * 4;
#pragma unroll
        for (int j = 0; j < 4; ++j) {
            const int jt = (nt0 + j) >> 1;
            const int qpart = ((nt0 + j) * 2 + (q >> 1)) & 3;
#pragma unroll
            for (int i = 0; i < 4; ++i) {
                short4v s4;
#pragma unroll
                for (int r = 0; r < 4; ++r) s4[r] = f2bf(acc[i][j][r]);
                *(short4v*)(dst + (((size_t)jt * 4 + i) * 64 + qpart * 16 + c) * 8 + e0) = s4;
            }
        }
    }
}

// ============ K2: attention — barrier-free, q-scale folded, 2 i-tiles ======
// PV issued transposed (V-frag as A, P-frag as B): D[m=d][n=i] so the aop
// scatter is contiguous short4 and inv is one scalar per u.
__global__ __launch_bounds__(256) void attn_mfma(const short* __restrict__ qp,
                                                 const short* __restrict__ kp,
                                                 const short* __restrict__ vp,
                                                 const float* __restrict__ ssq,
                                                 short* __restrict__ aop) {
    __shared__ __align__(16) short pt[4][16][40];  // per-wave P tile, 80B pitch
    const int t = threadIdx.x, lane = t & 63, wv = t >> 6;
    const int bh = blockIdx.y, b = bh >> 3, h = bh & 7;
    const int it0 = (blockIdx.x * 4 + wv) * 2;  // 2 i-tiles per wave
    const int c = lane & 15, q = lane >> 4;

    // per-d q-scale: 10/(nq[d]*nk[d]), d = st*32 + q*8 + e
    const float* sq_q = ssq + (size_t)b * 1024 + h * 64;
    const float* sq_k = sq_q + 512;
    float scl[2][8];
#pragma unroll
    for (int st = 0; st < 2; ++st) {
        const int d0 = st * 32 + q * 8;
        float4v q0 = *(const float4v*)(sq_q + d0);
        float4v q1 = *(const float4v*)(sq_q + d0 + 4);
        float4v k0 = *(const float4v*)(sq_k + d0);
        float4v k1 = *(const float4v*)(sq_k + d0 + 4);
#pragma unroll
        for (int e = 0; e < 4; ++e) {
            scl[st][e] = 10.f * rsqrtf(q0[e] * k0[e]);
            scl[st][4 + e] = 10.f * rsqrtf(q1[e] * k1[e]);
        }
    }

    short8 aq[2][2];
#pragma unroll
    for (int u = 0; u < 2; ++u) {
        const short* qpb = qp + (size_t)bh * 65536 + (size_t)(it0 + u) * 1024 + lane * 8;
#pragma unroll
        for (int st = 0; st < 2; ++st) {
            short8 raw = *(const short8*)(qpb + st * 512);
#pragma unroll
            for (int e = 0; e < 8; ++e) aq[u][st][e] = f2bf(bf2f(raw[e]) * scl[st][e]);
        }
    }

    short8 ones;
#pragma unroll
    for (int e = 0; e < 8; ++e) ones[e] = (short)0x3F80;  // bf16(1.0)

    float4v acc[2][4], accS[2];
#pragma unroll
    for (int u = 0; u < 2; ++u) {
        accS[u] = (float4v){0.f, 0.f, 0.f, 0.f};
#pragma unroll
        for (int dt = 0; dt < 4; ++dt) acc[u][dt] = (float4v){0.f, 0.f, 0.f, 0.f};
    }

    for (int jt = 0; jt < 32; ++jt) {
        const short* kbb = kp + (size_t)bh * 65536 + (size_t)jt * 2048 + lane * 8;
        short8 bk00 = *(const short8*)kbb;
        short8 bk01 = *(const short8*)(kbb + 512);
        short8 bk10 = *(const short8*)(kbb + 1024);
        short8 bk11 = *(const short8*)(kbb + 1536);
        const short* vbb = vp + (size_t)bh * 65536 + (size_t)jt * 2048 + lane * 8;
        short8 bv0 = *(const short8*)vbb;
        short8 bv1 = *(const short8*)(vbb + 512);
        short8 bv2 = *(const short8*)(vbb + 1024);
        short8 bv3 = *(const short8*)(vbb + 1536);

#pragma unroll
        for (int u = 0; u < 2; ++u) {
            // S^T = K.Q'^T: C col axis = i
            float4v s0 = (float4v){0.f, 0.f, 0.f, 0.f};
            float4v s1 = (float4v){0.f, 0.f, 0.f, 0.f};
            s0 = __builtin_amdgcn_mfma_f32_16x16x32_bf16(bk00, aq[u][0], s0, 0, 0, 0);
            s0 = __builtin_amdgcn_mfma_f32_16x16x32_bf16(bk01, aq[u][1], s0, 0, 0, 0);
            s1 = __builtin_amdgcn_mfma_f32_16x16x32_bf16(bk10, aq[u][0], s1, 0, 0, 0);
            s1 = __builtin_amdgcn_mfma_f32_16x16x32_bf16(bk11, aq[u][1], s1, 0, 0, 0);

            // P^T = exp(S^T) -> truncate bf16 pairs -> per-wave LDS tile
            int* ptw = (int*)&pt[wv][c][0];
#pragma unroll
            for (int jh = 0; jh < 2; ++jh) {
                float4v s = jh ? s1 : s0;
                unsigned u0 = __float_as_uint(__expf(s[0]));
                unsigned u1 = __float_as_uint(__expf(s[1]));
                unsigned u2 = __float_as_uint(__expf(s[2]));
                unsigned u3 = __float_as_uint(__expf(s[3]));
                ptw[jh * 8 + q * 2]     = (int)((u1 & 0xFFFF0000u) | (u0 >> 16));
                ptw[jh * 8 + q * 2 + 1] = (int)((u3 & 0xFFFF0000u) | (u2 >> 16));
            }
            short8 ap = *(const short8*)&pt[wv][c][q * 8];  // P[i=c][j=q*8+e]

            // transposed PV: D[m=d][n=i]
            acc[u][0] = __builtin_amdgcn_mfma_f32_16x16x32_bf16(bv0, ap, acc[u][0], 0, 0, 0);
            acc[u][1] = __builtin_amdgcn_mfma_f32_16x16x32_bf16(bv1, ap, acc[u][1], 0, 0, 0);
            acc[u][2] = __builtin_amdgcn_mfma_f32_16x16x32_bf16(bv2, ap, acc[u][2], 0, 0, 0);
            acc[u][3] = __builtin_amdgcn_mfma_f32_16x16x32_bf16(bv3, ap, acc[u][3], 0, 0, 0);
            accS[u]   = __builtin_amdgcn_mfma_f32_16x16x32_bf16(ones, ap, accS[u], 0, 0, 0);
        }
    }

    // contiguous short4 stores into out_proj B-frag order:
    // ch = h*64 + dt*16 + q*4 + r, s = it*16 + c
    short* ab = aop + (size_t)b * 524288;
    const int e0 = (q & 1) * 4;
#pragma unroll
    for (int u = 0; u < 2; ++u) {
        const int it = it0 + u;
        const float inv = 1.0f / accS[u][0];  // denominator for i = c
#pragma unroll
        for (int dt = 0; dt < 4; ++dt) {
            const int kt = h * 2 + (dt >> 1);
            const int ln = ((dt * 2 + (q >> 1)) & 3) * 16 + c;
            short4v s4;
#pragma unroll
            for (int r = 0; r < 4; ++r) s4[r] = f2bf(acc[u][dt][r] * inv);
            *(short4v*)(ab + (((size_t)kt * 64 + it) * 64 + ln) * 8 + e0) = s4;
        }
    }
}

// ============ K3: out projection — LDS-free, barrier-free frag GEMM =========
__global__ __launch_bounds__(256) void out_proj(const short* __restrict__ wp,
                                                const short* __restrict__ aop,
                                                const float* __restrict__ bias,
                                                float* __restrict__ out) {
    const int t = threadIdx.x, lane = t & 63, w = t >> 6;
    const int nt = blockIdx.x, b = blockIdx.y;
    const int c = lane & 15, q = lane >> 4;

    const short* bp = aop + ((size_t)b * 1024 + nt) * 512 + lane * 8;
    const short* ap = wp + (size_t)lane * 8;

    float4v acc[4];
#pragma unroll
    for (int i = 0; i < 4; ++i) acc[i] = (float4v){0.f, 0.f, 0.f, 0.f};

#pragma unroll 4
    for (int kt = 0; kt < 16; ++kt) {
        short8 bf_ = *(const short8*)(bp + (size_t)kt * 32768);
#pragma unroll
        for (int i = 0; i < 4; ++i) {
            short8 af = *(const short8*)(ap + (size_t)((w * 4 + i) * 16 + kt) * 512);
            acc[i] = __builtin_amdgcn_mfma_f32_16x16x32_bf16(af, bf_, acc[i], 0, 0, 0);
        }
    }

    float* ob = out + (size_t)b * CIN * SEQ;
#pragma unroll
    for (int i = 0; i < 4; ++i)
#pragma unroll
        for (int r = 0; r < 4; ++r) {
            const int o = w * 64 + i * 16 + q * 4 + r;
            ob[(size_t)o * SEQ + nt * 16 + c] = acc[i][r] + bias[o];
        }
}

extern "C" void kernel_launch(void* const* d_in, const int* in_sizes, int n_in,
                              void* d_out, int out_size, void* d_ws, size_t ws_size,
                              hipStream_t stream) {
    const float* x = (const float*)d_in[0];
    const float* w_qkv = (const float*)d_in[1];
    const float* w_out = (const float*)d_in[2];
    const float* b_out = (const float*)d_in[3];
    float* out = (float*)d_out;

    char* wsp = (char*)d_ws;
    short* qp  = (short*)wsp;                        // 8.39 MB
    short* kp  = (short*)(wsp + 8388608);            // 8.39 MB
    short* vp  = (short*)(wsp + 16777216);           // 8.39 MB
    short* aop = (short*)(wsp + 25165824);           // 8.39 MB
    short* wpk = (short*)(wsp + 33554432);           // 0.26 MB
    float* ssq = (float*)(wsp + 33816576);           // 32 KB
    short* xp  = (short*)(wsp + 33849344);           // 4.19 MB
    short* wqp = (short*)(wsp + 38043648);           // 0.79 MB (total 38.8 MB)

    pack_all<<<dim3(1281), 256, 0, stream>>>(x, w_qkv, w_out, xp, wqp, wpk, ssq);
    qkv_frag<<<dim3(16, 6, 8), 256, 0, stream>>>(xp, wqp, qp, kp, vp, ssq);
    attn_mfma<<<dim3(8, 64), 256, 0, stream>>>(qp, kp, vp, ssq, aop);
    out_proj<<<dim3(64, 8), 256, 0, stream>>>(wpk, aop, b_out, out);
}